// Round 10
// baseline (252.003 us; speedup 1.0000x reference)
//
#include <hip/hip_runtime.h>

typedef __attribute__((ext_vector_type(8))) short short8;
typedef __attribute__((ext_vector_type(4))) float f32x4;
typedef __attribute__((ext_vector_type(4))) int i32x4;

#define NSEQ 4096
#define MSEQ 1024
#define HID  512
#define CTXD 768

static __device__ __forceinline__ unsigned short f2bf(float f) {
  union { float f; unsigned u; } v; v.f = f;
  return (unsigned short)((v.u + 0x7fffu + ((v.u >> 16) & 1u)) >> 16);
}

static __device__ __forceinline__ void gld16(const void* g, void* l) {
  __builtin_amdgcn_global_load_lds((const __attribute__((address_space(1))) void*)g,
                                   (__attribute__((address_space(3))) void*)l, 16, 0, 0);
}
static __device__ __forceinline__ void gld4(const void* g, void* l) {
  __builtin_amdgcn_global_load_lds((const __attribute__((address_space(1))) void*)g,
                                   (__attribute__((address_space(3))) void*)l, 4, 0, 0);
}

// ---------------- weight transpose: W[K][N] f32 -> WT[N][K] bf16 ----------------
__global__ void k_transpose(const float* __restrict__ W, unsigned short* __restrict__ WT,
                            int K, int N) {
  __shared__ float tile[32][33];
  int k0 = blockIdx.x * 32, n0 = blockIdx.y * 32;
  int tx = threadIdx.x, ty = threadIdx.y;
#pragma unroll
  for (int i = 0; i < 32; i += 8)
    tile[ty + i][tx] = W[(size_t)(k0 + ty + i) * N + n0 + tx];
  __syncthreads();
#pragma unroll
  for (int i = 0; i < 32; i += 8)
    WT[(size_t)(n0 + ty + i) * K + k0 + tx] = f2bf(tile[tx][ty + i]);
}

// ---------------- f32 -> bf16 cast, vectorized ----------------
__global__ void k_cast(const float* __restrict__ in, unsigned short* __restrict__ out, int n8) {
  int i = blockIdx.x * blockDim.x + threadIdx.x;
  int stride = gridDim.x * blockDim.x;
  for (; i < n8; i += stride) {
    f32x4 v0 = *(const f32x4*)(in + (size_t)i * 8);
    f32x4 v1 = *(const f32x4*)(in + (size_t)i * 8 + 4);
    unsigned short tmp[8] __attribute__((aligned(16)));
    tmp[0] = f2bf(v0[0]); tmp[1] = f2bf(v0[1]); tmp[2] = f2bf(v0[2]); tmp[3] = f2bf(v0[3]);
    tmp[4] = f2bf(v1[0]); tmp[5] = f2bf(v1[1]); tmp[6] = f2bf(v1[2]); tmp[7] = f2bf(v1[3]);
    *(i32x4*)(out + (size_t)i * 8) = *(const i32x4*)tmp;
  }
}

// ---------------- GEMM 128x128 (R2-proven): C = A[M][K] * BT[N][K]^T ------------
// ZMODE 0: grid (mx,ny,nz). ZMODE 2: flat grid, z=bid&7, r=bid>>3, m=r>>3, n=r&7.
template<int BIAS_MODE, bool RES, bool OUT_BF16, int ZMODE>
__global__ __launch_bounds__(256, 2) void k_gemm(
    const unsigned short* __restrict__ A, const unsigned short* __restrict__ B,
    const float* __restrict__ bias, const float* __restrict__ resv,
    void* __restrict__ Cv, int M, int N, int K,
    long sA, long sB, long sC, long sR) {
  __shared__ __align__(16) char lds[65536];
  const int t = threadIdx.x, lane = t & 63, wid = t >> 6;
  const int wr = wid >> 1, wc = wid & 1;
  int m0, n0, z;
  if (ZMODE == 2) {
    int bid = blockIdx.x; z = bid & 7; int r = bid >> 3;
    m0 = (r >> 3) * 128; n0 = (r & 7) * 128;
  } else {
    m0 = blockIdx.x * 128; n0 = blockIdx.y * 128; z = blockIdx.z;
  }
  const unsigned short* Ab = A + (size_t)z * sA;
  const unsigned short* Bb = B + (size_t)z * sB;

  const f32x4 fz = {0.f, 0.f, 0.f, 0.f};
  f32x4 acc[4][4];
#pragma unroll
  for (int i = 0; i < 4; i++)
#pragma unroll
    for (int j = 0; j < 4; j++) acc[i][j] = fz;

  const int srow = t >> 3;      // 0..31
  const int schunk = t & 7;

  auto stage = [&](int kk, int buf) {
    const char* a8 = (const char*)Ab;
    const char* b8 = (const char*)Bb;
#pragma unroll
    for (int i = 0; i < 4; i++) {
      int row = i * 32 + srow;
      gld16(a8 + ((size_t)(m0 + row) * K + kk) * 2 + ((schunk ^ (row & 7)) << 4),
            lds + buf * 32768 + i * 4096 + wid * 1024);
    }
#pragma unroll
    for (int i = 0; i < 4; i++) {
      int row = i * 32 + srow;
      gld16(b8 + ((size_t)(n0 + row) * K + kk) * 2 + ((schunk ^ (row & 7)) << 4),
            lds + buf * 32768 + 16384 + i * 4096 + wid * 1024);
    }
  };

  stage(0, 0);
  int buf = 0;
  for (int kk = 0; kk < K; kk += 64) {
    if (kk + 64 < K) {
      stage(kk + 64, buf ^ 1);
      asm volatile("s_waitcnt vmcnt(8)" ::: "memory");
    } else {
      asm volatile("s_waitcnt vmcnt(0)" ::: "memory");
    }
    __builtin_amdgcn_s_barrier();
    const char* As = lds + buf * 32768;
    const char* Bs = As + 16384;
#pragma unroll
    for (int ks = 0; ks < 2; ks++) {
      short8 af[4], bfr[4];
#pragma unroll
      for (int i = 0; i < 4; i++) {
        int r = wr * 64 + i * 16 + (lane & 15);
        af[i] = *(const short8*)(As + r * 128 +
                 (((unsigned)(ks * 64 + (lane >> 4) * 16)) ^ ((unsigned)(r & 7) << 4)));
      }
#pragma unroll
      for (int i = 0; i < 4; i++) {
        int r = wc * 64 + i * 16 + (lane & 15);
        bfr[i] = *(const short8*)(Bs + r * 128 +
                 (((unsigned)(ks * 64 + (lane >> 4) * 16)) ^ ((unsigned)(r & 7) << 4)));
      }
#pragma unroll
      for (int i = 0; i < 4; i++)
#pragma unroll
        for (int j = 0; j < 4; j++)
          acc[i][j] = __builtin_amdgcn_mfma_f32_16x16x32_bf16(af[i], bfr[j], acc[i][j], 0, 0, 0);
    }
    asm volatile("s_waitcnt lgkmcnt(0)" ::: "memory");
    __builtin_amdgcn_s_barrier();
    buf ^= 1;
  }

  const float* res = RES ? (resv + (size_t)z * sR) : nullptr;
  char* Cb = (char*)Cv + (size_t)z * sC * (OUT_BF16 ? 2 : 4);
#pragma unroll
  for (int i = 0; i < 4; i++) {
#pragma unroll
    for (int jj = 0; jj < 4; jj++) {
      int row = m0 + wr * 64 + i * 16 + (lane >> 4) * 4 + jj;
#pragma unroll
      for (int j = 0; j < 4; j++) {
        int col = n0 + wc * 64 + j * 16 + (lane & 15);
        float v = acc[i][j][jj];
        if (BIAS_MODE == 1) v += bias[col];
        if (BIAS_MODE == 2) v += bias[row];
        if (RES) v += res[(size_t)row * N + col];
        if (OUT_BF16) ((unsigned short*)Cb)[(size_t)row * N + col] = f2bf(v);
        else          ((float*)Cb)[(size_t)row * N + col] = v;
      }
    }
  }
}

// ---------------- GEMM 256x256, BK=32, 8 waves (2x4), 3-buffer ring -------------
// ZMODE 0: grid (mx,ny,nz). ZMODE 1: flat grid, z=bid&7, r=bid>>3, m=r>>1, n=r&1.
template<int BIAS_MODE, bool RES, bool OUT_BF16, int ZMODE>
__global__ __launch_bounds__(512, 1) void k_gemm3(
    const unsigned short* __restrict__ A, const unsigned short* __restrict__ B,
    const float* __restrict__ bias, const float* __restrict__ resv,
    void* __restrict__ Cv, int M, int N, int K,
    long sA, long sB, long sC, long sR) {
  __shared__ __align__(16) char lds[98304];   // 3 x (A 16K + B 16K)
  const int t = threadIdx.x, lane = t & 63, wid = t >> 6;
  const int wr = wid >> 2, wc = wid & 3;
  const int l15 = lane & 15, g = lane >> 4;
  int m0, n0, z;
  if (ZMODE == 1) {
    int bid = blockIdx.x; z = bid & 7; int r = bid >> 3;
    m0 = (r >> 1) * 256; n0 = (r & 1) * 256;
  } else {
    m0 = blockIdx.x * 256; n0 = blockIdx.y * 256; z = blockIdx.z;
  }
  const unsigned short* Ab = A + (size_t)z * sA;
  const unsigned short* Bb = B + (size_t)z * sB;

  const f32x4 fz = {0.f, 0.f, 0.f, 0.f};
  f32x4 acc[8][4];
#pragma unroll
  for (int i = 0; i < 8; i++)
#pragma unroll
    for (int j = 0; j < 4; j++) acc[i][j] = fz;

  // per-lane inverse map for staging: LDS byte p -> logical (row, colbyte)
  int rS[2], cS[2];
#pragma unroll
  for (int u = 0; u < 2; u++) {
    int p = u * 8192 + wid * 1024 + lane * 16;
    int L = p >> 7;
    int q = (p & 127) ^ ((L & 7) << 4);
    rS[u] = 2 * L + (q >> 6);
    cS[u] = q & 63;
  }

  auto stageA = [&](int kk, int buf, int u) {
    gld16((const char*)Ab + ((size_t)(m0 + rS[u]) * K + kk) * 2 + cS[u],
          lds + buf * 32768 + u * 8192 + wid * 1024);
  };
  auto stageB = [&](int kk, int buf, int u) {
    gld16((const char*)Bb + ((size_t)(n0 + rS[u]) * K + kk) * 2 + cS[u],
          lds + buf * 32768 + 16384 + u * 8192 + wid * 1024);
  };

  auto ldso = [&](int r, int gg) -> unsigned {
    unsigned L = (unsigned)(r >> 1);
    return L * 128 + ((((unsigned)(r & 1)) * 64 + (unsigned)gg * 16) ^ ((L & 7) << 4));
  };

  const int NT = K >> 5;
#pragma unroll
  for (int u = 0; u < 2; u++) { stageA(0, 0, u); }
#pragma unroll
  for (int u = 0; u < 2; u++) { stageB(0, 0, u); }
#pragma unroll
  for (int u = 0; u < 2; u++) { stageA(32, 1, u); }
#pragma unroll
  for (int u = 0; u < 2; u++) { stageB(32, 1, u); }

  for (int tt = 0; tt < NT; tt++) {
    if (tt + 1 < NT) { asm volatile("s_waitcnt vmcnt(4)" ::: "memory"); }
    else             { asm volatile("s_waitcnt vmcnt(0)" ::: "memory"); }
    __builtin_amdgcn_s_barrier();
    const char* As = lds + (tt % 3) * 32768;
    const char* Bs = As + 16384;
    const int kk2 = (tt + 2) << 5;
    const bool st = kk2 < K;
    const int bn = (tt + 2) % 3;

    short8 bfr[4];
#pragma unroll
    for (int p = 0; p < 2; p++) {
      short8 af[4];
#pragma unroll
      for (int fi = 0; fi < 4; fi++) {
        int r = wr * 128 + (p * 4 + fi) * 16 + l15;
        af[fi] = *(const short8*)(As + ldso(r, g));
      }
      if (p == 0) {
#pragma unroll
        for (int fj = 0; fj < 4; fj++) {
          int r = wc * 64 + fj * 16 + l15;
          bfr[fj] = *(const short8*)(Bs + ldso(r, g));
        }
        if (st) { stageA(kk2, bn, 0); stageA(kk2, bn, 1); }
      } else {
        if (st) { stageB(kk2, bn, 0); stageB(kk2, bn, 1); }
      }
      asm volatile("s_waitcnt lgkmcnt(0)" ::: "memory");
      __builtin_amdgcn_s_setprio(1);
#pragma unroll
      for (int fi = 0; fi < 4; fi++)
#pragma unroll
        for (int fj = 0; fj < 4; fj++)
          acc[p * 4 + fi][fj] =
              __builtin_amdgcn_mfma_f32_16x16x32_bf16(af[fi], bfr[fj], acc[p * 4 + fi][fj], 0, 0, 0);
      __builtin_amdgcn_s_setprio(0);
      __builtin_amdgcn_s_barrier();
    }
  }

  const float* res = RES ? (resv + (size_t)z * sR) : nullptr;
  char* Cb = (char*)Cv + (size_t)z * sC * (OUT_BF16 ? 2 : 4);
#pragma unroll
  for (int i = 0; i < 8; i++) {
#pragma unroll
    for (int jj = 0; jj < 4; jj++) {
      int row = m0 + wr * 128 + i * 16 + g * 4 + jj;
#pragma unroll
      for (int j = 0; j < 4; j++) {
        int col = n0 + wc * 64 + j * 16 + l15;
        float v = acc[i][j][jj];
        if (BIAS_MODE == 1) v += bias[col];
        if (BIAS_MODE == 2) v += bias[row];
        if (RES) v += res[(size_t)row * N + col];
        if (OUT_BF16) ((unsigned short*)Cb)[(size_t)row * N + col] = f2bf(v);
        else          ((float*)Cb)[(size_t)row * N + col] = v;
      }
    }
  }
}

// ---------------- QK^T + softmax -> normalized P^ (bf16), 2 blocks/CU -----------
// Block: 32 q-rows x full M=1024, 4 waves (256 thr), ~66.7KB LDS -> 2 blocks/CU
// so one block's softmax/store overlaps the other's K-loop. Tiles [256m][32hid]
// (16KB) + Q [32][32] (2KB), ring of 3, prefetch distance 2, boundary vmcnt(6)
// (4 K gld16 + 2 Q gld4 per thread/tile). k_gemm3's proven 64B-row swizzle +
// inverse-map staging. S in regs (128 f32/thread). LDS-staged coalesced P^ store.
__global__ __launch_bounds__(256, 2) void k_qks(
    const unsigned short* __restrict__ qb,   // [B*4096][512] bf16
    const unsigned short* __restrict__ kb,   // [B*1024][512] bf16
    unsigned short* __restrict__ phat) {     // [B][4096][1024] bf16 (normalized)
  __shared__ __align__(16) char lds[66688];
  char* Kr = lds;                          // ring: 3 x 16384 = 49152
  char* Qr = lds + 49152;                  // ring: 3 x 2048  = 6144 -> 55296
  char* Ps = lds;                          // [32][2048B] staging (epilogue, 64KB)
  float* pmax = (float*)(lds + 65536);     // [4][32]
  float* psum = (float*)(lds + 66048);     // [4][32]
  float* gbuf = (float*)(lds + 66560);     // [32]

  const int t = threadIdx.x, lane = t & 63, wid = t >> 6;  // wid 0..3
  const int g = lane >> 4, l15 = lane & 15;
  const int bid = blockIdx.x;
  const int b = bid & 7;                   // batch -> XCD affinity
  const int n0 = (bid >> 3) * 32;
  const char* qbase = (const char*)(qb + ((size_t)b * NSEQ + n0) * HID);
  const char* kbase = (const char*)(kb + (size_t)b * MSEQ * HID);

  // inverse maps (k_gemm3 pattern): K at 16B grain (4 steps), Q at 4B grain (2)
  int rK[4], cK[4];
#pragma unroll
  for (int u = 0; u < 4; u++) {
    int p = u * 4096 + wid * 1024 + lane * 16;
    int L = p >> 7;
    int q = (p & 127) ^ ((L & 7) << 4);
    rK[u] = 2 * L + (q >> 6);              // 0..255
    cK[u] = q & 63;
  }
  int rQ[2], cQ[2];
#pragma unroll
  for (int j = 0; j < 2; j++) {
    int p = j * 1024 + wid * 256 + lane * 4;
    int L = p >> 7;
    int q = (p & 127) ^ ((L & 7) << 4);
    rQ[j] = 2 * L + (q >> 6);              // 0..31
    cQ[j] = q & 63;
  }

  // stage tile tt2 (mc2 = tt2>>4 in 0..3, ks2 = tt2&15) into ring slot bn
  auto stage = [&](int tt2, int bn) {
    int mc2 = tt2 >> 4, ks2 = tt2 & 15;
#pragma unroll
    for (int u = 0; u < 4; u++)
      gld16(kbase + ((size_t)(mc2 * 256 + rK[u]) * HID + ks2 * 32) * 2 + cK[u],
            Kr + bn * 16384 + u * 4096 + wid * 1024);
#pragma unroll
    for (int j = 0; j < 2; j++)
      gld4(qbase + ((size_t)rQ[j] * HID + ks2 * 32) * 2 + cQ[j],
           Qr + bn * 2048 + j * 1024 + wid * 256);
  };

  auto ldso = [&](int r, int gg) -> unsigned {
    unsigned L = (unsigned)(r >> 1);
    return L * 128 + ((((unsigned)(r & 1)) * 64 + (unsigned)gg * 16) ^ ((L & 7) << 4));
  };

  const f32x4 fz = {0.f, 0.f, 0.f, 0.f};
  f32x4 s[2][16];
#pragma unroll
  for (int qf = 0; qf < 2; qf++)
#pragma unroll
    for (int mf = 0; mf < 16; mf++) s[qf][mf] = fz;

  stage(0, 0);
  stage(1, 1);

#pragma unroll
  for (int mc = 0; mc < 4; mc++) {
    for (int ks2 = 0; ks2 < 16; ks2++) {
      const int tt = mc * 16 + ks2;
      if (tt + 1 < 64) { asm volatile("s_waitcnt vmcnt(6)" ::: "memory"); }
      else             { asm volatile("s_waitcnt vmcnt(0)" ::: "memory"); }
      __builtin_amdgcn_s_barrier();
      const char* Kc = Kr + (tt % 3) * 16384;
      const char* Qc = Qr + (tt % 3) * 2048;
      short8 aq[2], bk[4];
#pragma unroll
      for (int qf = 0; qf < 2; qf++) {
        int r = qf * 16 + l15;
        aq[qf] = *(const short8*)(Qc + ldso(r, g));
      }
#pragma unroll
      for (int f = 0; f < 4; f++) {
        int r = wid * 64 + f * 16 + l15;
        bk[f] = *(const short8*)(Kc + ldso(r, g));
      }
      if (tt + 2 < 64) stage(tt + 2, (tt + 2) % 3);
      asm volatile("s_waitcnt lgkmcnt(0)" ::: "memory");
      __builtin_amdgcn_s_setprio(1);
#pragma unroll
      for (int qf = 0; qf < 2; qf++)
#pragma unroll
        for (int f = 0; f < 4; f++)
          s[qf][mc * 4 + f] =
              __builtin_amdgcn_mfma_f32_16x16x32_bf16(aq[qf], bk[f], s[qf][mc * 4 + f], 0, 0, 0);
      __builtin_amdgcn_s_setprio(0);
      __builtin_amdgcn_s_barrier();
    }
  }
  // s[qf][mc*4+f] holds m = mc*256 + wid*64 + f*16 + l15, q-row = qf*16 + g*4 + jj

  // ---- softmax (exact, full row) ----
  const float scale = 0.044194173824159216f;  // 512^-0.5
#pragma unroll
  for (int qf = 0; qf < 2; qf++)
#pragma unroll
    for (int mf = 0; mf < 16; mf++)
#pragma unroll
      for (int jj = 0; jj < 4; jj++) s[qf][mf][jj] *= scale;

  float rmax[2][4];
#pragma unroll
  for (int qf = 0; qf < 2; qf++)
#pragma unroll
    for (int jj = 0; jj < 4; jj++) {
      float m = s[qf][0][jj];
#pragma unroll
      for (int mf = 1; mf < 16; mf++) m = fmaxf(m, s[qf][mf][jj]);
      rmax[qf][jj] = m;
    }
#pragma unroll
  for (int d = 1; d < 16; d <<= 1)
#pragma unroll
    for (int qf = 0; qf < 2; qf++)
#pragma unroll
      for (int jj = 0; jj < 4; jj++)
        rmax[qf][jj] = fmaxf(rmax[qf][jj], __shfl_xor(rmax[qf][jj], d, 64));
  if (l15 == 0) {
#pragma unroll
    for (int qf = 0; qf < 2; qf++)
#pragma unroll
      for (int jj = 0; jj < 4; jj++)
        pmax[wid * 32 + qf * 16 + g * 4 + jj] = rmax[qf][jj];
  }
  __syncthreads();
  if (t < 32) {
    float m = pmax[t];
#pragma unroll
    for (int ww = 1; ww < 4; ww++) m = fmaxf(m, pmax[ww * 32 + t]);
    gbuf[t] = m;
  }
  __syncthreads();
  float fm[2][4], rs[2][4];
#pragma unroll
  for (int qf = 0; qf < 2; qf++)
#pragma unroll
    for (int jj = 0; jj < 4; jj++) {
      fm[qf][jj] = gbuf[qf * 16 + g * 4 + jj];
      rs[qf][jj] = 0.f;
    }
#pragma unroll
  for (int qf = 0; qf < 2; qf++)
#pragma unroll
    for (int mf = 0; mf < 16; mf++)
#pragma unroll
      for (int jj = 0; jj < 4; jj++) {
        float p = __expf(s[qf][mf][jj] - fm[qf][jj]);
        s[qf][mf][jj] = p;
        rs[qf][jj] += p;
      }
#pragma unroll
  for (int d = 1; d < 16; d <<= 1)
#pragma unroll
    for (int qf = 0; qf < 2; qf++)
#pragma unroll
      for (int jj = 0; jj < 4; jj++)
        rs[qf][jj] += __shfl_xor(rs[qf][jj], d, 64);
  __syncthreads();
  if (l15 == 0) {
#pragma unroll
    for (int qf = 0; qf < 2; qf++)
#pragma unroll
      for (int jj = 0; jj < 4; jj++)
        psum[wid * 32 + qf * 16 + g * 4 + jj] = rs[qf][jj];
  }
  __syncthreads();
  if (t < 32) {
    float ssum = psum[t];
#pragma unroll
    for (int ww = 1; ww < 4; ww++) ssum += psum[ww * 32 + t];
    gbuf[t] = 1.0f / ssum;
  }
  __syncthreads();   // gbuf ready; K/Q rings dead -> Ps may overwrite

  // ---- P^ (normalized, bf16) -> LDS [32][2048B], XOR swizzle (row&15)<<4 ----
#pragma unroll
  for (int qf = 0; qf < 2; qf++)
#pragma unroll
    for (int jj = 0; jj < 4; jj++) {
      int row = qf * 16 + g * 4 + jj;
      float fi = gbuf[row];
      char* pr = Ps + row * 2048;
      unsigned cr = (unsigned)(row & 15) << 4;
#pragma unroll
      for (int mf = 0; mf < 16; mf++) {
        int col = (mf >> 2) * 256 + wid * 64 + (mf & 3) * 16 + l15;
        *(unsigned short*)(pr + (((unsigned)(col * 2)) ^ cr)) = f2bf(s[qf][mf][jj] * fi);
      }
    }
  __syncthreads();

  // ---- coalesced store: wave w -> rows [w*8, w*8+8), 1KB per instruction ----
  {
    unsigned short* pb = phat + (size_t)b * NSEQ * MSEQ;
#pragma unroll
    for (int r8 = 0; r8 < 8; r8++) {
      int row = wid * 8 + r8;
      unsigned cr = (unsigned)(row & 15) << 4;
      char* src = Ps + row * 2048;
      char* dst = (char*)(pb + (size_t)(n0 + row) * MSEQ);
#pragma unroll
      for (int half = 0; half < 2; half++) {
        unsigned q = (unsigned)(half * 1024 + lane * 16);
        i32x4 v = *(const i32x4*)(src + (q ^ cr));
        *(i32x4*)(dst + q) = v;
      }
    }
  }
}

// ---------------- launch ----------------
extern "C" void kernel_launch(void* const* d_in, const int* in_sizes, int n_in,
                              void* d_out, int out_size, void* d_ws, size_t ws_size,
                              hipStream_t stream) {
  (void)in_sizes; (void)n_in; (void)out_size; (void)ws_size;
  const float* x   = (const float*)d_in[0];
  const float* ctx = (const float*)d_in[1];
  const float* Wq  = (const float*)d_in[2];
  const float* bq  = (const float*)d_in[3];
  const float* Wk  = (const float*)d_in[4];
  const float* bk  = (const float*)d_in[5];
  const float* Wv  = (const float*)d_in[6];
  const float* bv  = (const float*)d_in[7];
  const float* Wo  = (const float*)d_in[8];
  const float* bo  = (const float*)d_in[9];
  float* out = (float*)d_out;

  char* ws = (char*)d_ws;
  unsigned short* qb   = (unsigned short*)(ws);              // 33,554,432
  unsigned short* kbuf = (unsigned short*)(ws + 33554432);   //  8,388,608
  unsigned short* vT   = (unsigned short*)(ws + 41943040);   //  8,388,608
  unsigned short* ctxb = (unsigned short*)(ws + 50331648);   // 33,554,432
  unsigned short* WqT  = (unsigned short*)(ws + 83886080);   //    524,288
  unsigned short* WkT  = (unsigned short*)(ws + 84410368);   //    786,432
  unsigned short* WvT  = (unsigned short*)(ws + 85196800);   //    786,432
  unsigned short* WoT  = (unsigned short*)(ws + 85983232);   //    524,288 -> 86,507,520
  // phat overlays xb+cb (both dead by k_qks time)
  unsigned short* phat = (unsigned short*)(ws + 86507520);   // 67,108,864 -> 153,616,384
  unsigned short* xb   = (unsigned short*)(ws + 86507520);   // 33,554,432
  unsigned short* cb   = (unsigned short*)(ws + 120061952);  // 12,582,912

  dim3 tb(32, 8);
  k_transpose<<<dim3(16, 16), tb, 0, stream>>>(Wq, WqT, 512, 512);
  k_transpose<<<dim3(24, 16), tb, 0, stream>>>(Wk, WkT, 768, 512);
  k_transpose<<<dim3(24, 16), tb, 0, stream>>>(Wv, WvT, 768, 512);
  k_transpose<<<dim3(16, 16), tb, 0, stream>>>(Wo, WoT, 512, 512);

  k_cast<<<dim3(2048), 256, 0, stream>>>(x,   xb, 2097152);
  k_cast<<<dim3(2048), 256, 0, stream>>>(ctx, cb,  786432);

  // q = x @ Wq + bq -> bf16 [32768][512]
  k_gemm3<1, false, true, 0><<<dim3(128, 2, 1), 512, 0, stream>>>(
      xb, WqT, bq, nullptr, qb, 32768, 512, 512, 0, 0, 0, 0);
  // k = ctx @ Wk + bk -> bf16 [8192][512]
  k_gemm<1, false, true, 0><<<dim3(64, 4, 1), 256, 0, stream>>>(
      cb, WkT, bk, nullptr, kbuf, 8192, 512, 768, 0, 0, 0, 0);
  // vT[b] = (ctx[b] @ Wv + bv)^T -> bf16 [8][512][1024]  (z->XCD affinity)
  k_gemm<2, false, true, 2><<<dim3(256), 256, 0, stream>>>(
      WvT, cb, bv, nullptr, vT, 512, 1024, 768, 0, (long)1024 * 768, (long)512 * 1024, 0);
  // P^ = softmax(q k^T * scale), normalized -> bf16 [8][4096][1024]
  k_qks<<<dim3(1024), 256, 0, stream>>>(qb, kbuf, phat);
  // ctx_out[b] = P^[b] @ vT[b]^T -> bf16 [8][4096][512]  (z->XCD affinity)
  k_gemm3<0, false, true, 1><<<dim3(256), 512, 0, stream>>>(
      phat, vT, nullptr, nullptr, ctxb, 4096, 512, 1024,
      (long)4096 * 1024, (long)512 * 1024, (long)4096 * 512, 0);
  // out = ctx_out @ Wo + bo + x -> f32
  k_gemm3<1, true, false, 0><<<dim3(128, 2, 1), 512, 0, stream>>>(
      ctxb, WoT, bo, x, out, 32768, 512, 512, 0, 0, 0, 0);
}

// Round 11
// 231.240 us; speedup vs baseline: 1.0898x; 1.0898x over previous
//
#include <hip/hip_runtime.h>

typedef __attribute__((ext_vector_type(8))) short short8;
typedef __attribute__((ext_vector_type(4))) float f32x4;
typedef __attribute__((ext_vector_type(4))) int i32x4;

#define NSEQ 4096
#define MSEQ 1024
#define HID  512
#define CTXD 768

static __device__ __forceinline__ unsigned short f2bf(float f) {
  union { float f; unsigned u; } v; v.f = f;
  return (unsigned short)((v.u + 0x7fffu + ((v.u >> 16) & 1u)) >> 16);
}
static __device__ __forceinline__ float bf2f(unsigned short u) {
  union { unsigned u; float f; } v; v.u = ((unsigned)u) << 16;
  return v.f;
}

static __device__ __forceinline__ void gld16(const void* g, void* l) {
  __builtin_amdgcn_global_load_lds((const __attribute__((address_space(1))) void*)g,
                                   (__attribute__((address_space(3))) void*)l, 16, 0, 0);
}

// ---------------- weight transpose: W[K][N] f32 -> WT[N][K] bf16 ----------------
__global__ void k_transpose(const float* __restrict__ W, unsigned short* __restrict__ WT,
                            int K, int N) {
  __shared__ float tile[32][33];
  int k0 = blockIdx.x * 32, n0 = blockIdx.y * 32;
  int tx = threadIdx.x, ty = threadIdx.y;
#pragma unroll
  for (int i = 0; i < 32; i += 8)
    tile[ty + i][tx] = W[(size_t)(k0 + ty + i) * N + n0 + tx];
  __syncthreads();
#pragma unroll
  for (int i = 0; i < 32; i += 8)
    WT[(size_t)(n0 + ty + i) * K + k0 + tx] = f2bf(tile[tx][ty + i]);
}

// ---------------- f32 -> bf16 cast, vectorized ----------------
__global__ void k_cast(const float* __restrict__ in, unsigned short* __restrict__ out, int n8) {
  int i = blockIdx.x * blockDim.x + threadIdx.x;
  int stride = gridDim.x * blockDim.x;
  for (; i < n8; i += stride) {
    f32x4 v0 = *(const f32x4*)(in + (size_t)i * 8);
    f32x4 v1 = *(const f32x4*)(in + (size_t)i * 8 + 4);
    unsigned short tmp[8] __attribute__((aligned(16)));
    tmp[0] = f2bf(v0[0]); tmp[1] = f2bf(v0[1]); tmp[2] = f2bf(v0[2]); tmp[3] = f2bf(v0[3]);
    tmp[4] = f2bf(v1[0]); tmp[5] = f2bf(v1[1]); tmp[6] = f2bf(v1[2]); tmp[7] = f2bf(v1[3]);
    *(i32x4*)(out + (size_t)i * 8) = *(const i32x4*)tmp;
  }
}

// ---------------- GEMM 128x128 (R2-proven): C = A[M][K] * BT[N][K]^T ------------
// ZMODE 0: grid (mx,ny,nz). ZMODE 2: flat grid, z=bid&7, r=bid>>3, m=r>>3, n=r&7.
template<int BIAS_MODE, bool RES, bool OUT_BF16, int ZMODE>
__global__ __launch_bounds__(256, 2) void k_gemm(
    const unsigned short* __restrict__ A, const unsigned short* __restrict__ B,
    const float* __restrict__ bias, const float* __restrict__ resv,
    void* __restrict__ Cv, int M, int N, int K,
    long sA, long sB, long sC, long sR) {
  __shared__ __align__(16) char lds[65536];
  const int t = threadIdx.x, lane = t & 63, wid = t >> 6;
  const int wr = wid >> 1, wc = wid & 1;
  int m0, n0, z;
  if (ZMODE == 2) {
    int bid = blockIdx.x; z = bid & 7; int r = bid >> 3;
    m0 = (r >> 3) * 128; n0 = (r & 7) * 128;
  } else {
    m0 = blockIdx.x * 128; n0 = blockIdx.y * 128; z = blockIdx.z;
  }
  const unsigned short* Ab = A + (size_t)z * sA;
  const unsigned short* Bb = B + (size_t)z * sB;

  const f32x4 fz = {0.f, 0.f, 0.f, 0.f};
  f32x4 acc[4][4];
#pragma unroll
  for (int i = 0; i < 4; i++)
#pragma unroll
    for (int j = 0; j < 4; j++) acc[i][j] = fz;

  const int srow = t >> 3;      // 0..31
  const int schunk = t & 7;

  auto stage = [&](int kk, int buf) {
    const char* a8 = (const char*)Ab;
    const char* b8 = (const char*)Bb;
#pragma unroll
    for (int i = 0; i < 4; i++) {
      int row = i * 32 + srow;
      gld16(a8 + ((size_t)(m0 + row) * K + kk) * 2 + ((schunk ^ (row & 7)) << 4),
            lds + buf * 32768 + i * 4096 + wid * 1024);
    }
#pragma unroll
    for (int i = 0; i < 4; i++) {
      int row = i * 32 + srow;
      gld16(b8 + ((size_t)(n0 + row) * K + kk) * 2 + ((schunk ^ (row & 7)) << 4),
            lds + buf * 32768 + 16384 + i * 4096 + wid * 1024);
    }
  };

  stage(0, 0);
  int buf = 0;
  for (int kk = 0; kk < K; kk += 64) {
    if (kk + 64 < K) {
      stage(kk + 64, buf ^ 1);
      asm volatile("s_waitcnt vmcnt(8)" ::: "memory");
    } else {
      asm volatile("s_waitcnt vmcnt(0)" ::: "memory");
    }
    __builtin_amdgcn_s_barrier();
    const char* As = lds + buf * 32768;
    const char* Bs = As + 16384;
#pragma unroll
    for (int ks = 0; ks < 2; ks++) {
      short8 af[4], bfr[4];
#pragma unroll
      for (int i = 0; i < 4; i++) {
        int r = wr * 64 + i * 16 + (lane & 15);
        af[i] = *(const short8*)(As + r * 128 +
                 (((unsigned)(ks * 64 + (lane >> 4) * 16)) ^ ((unsigned)(r & 7) << 4)));
      }
#pragma unroll
      for (int i = 0; i < 4; i++) {
        int r = wc * 64 + i * 16 + (lane & 15);
        bfr[i] = *(const short8*)(Bs + r * 128 +
                 (((unsigned)(ks * 64 + (lane >> 4) * 16)) ^ ((unsigned)(r & 7) << 4)));
      }
#pragma unroll
      for (int i = 0; i < 4; i++)
#pragma unroll
        for (int j = 0; j < 4; j++)
          acc[i][j] = __builtin_amdgcn_mfma_f32_16x16x32_bf16(af[i], bfr[j], acc[i][j], 0, 0, 0);
    }
    asm volatile("s_waitcnt lgkmcnt(0)" ::: "memory");
    __builtin_amdgcn_s_barrier();
    buf ^= 1;
  }

  const float* res = RES ? (resv + (size_t)z * sR) : nullptr;
  char* Cb = (char*)Cv + (size_t)z * sC * (OUT_BF16 ? 2 : 4);
#pragma unroll
  for (int i = 0; i < 4; i++) {
#pragma unroll
    for (int jj = 0; jj < 4; jj++) {
      int row = m0 + wr * 64 + i * 16 + (lane >> 4) * 4 + jj;
#pragma unroll
      for (int j = 0; j < 4; j++) {
        int col = n0 + wc * 64 + j * 16 + (lane & 15);
        float v = acc[i][j][jj];
        if (BIAS_MODE == 1) v += bias[col];
        if (BIAS_MODE == 2) v += bias[row];
        if (RES) v += res[(size_t)row * N + col];
        if (OUT_BF16) ((unsigned short*)Cb)[(size_t)row * N + col] = f2bf(v);
        else          ((float*)Cb)[(size_t)row * N + col] = v;
      }
    }
  }
}

// ---------------- GEMM 256x256, BK=32, 8 waves (2x4), 3-buffer ring -------------
// ZMODE 0: grid (mx,ny,nz). ZMODE 1: flat, z=bid&7, r=bid>>3, m=r>>1, n=r&1.
// ZMODE 3: flat, z=bid&7, r=bid>>3, m=r>>2, n=r&3.
template<int BIAS_MODE, bool RES, bool OUT_BF16, int ZMODE>
__global__ __launch_bounds__(512, 1) void k_gemm3(
    const unsigned short* __restrict__ A, const unsigned short* __restrict__ B,
    const float* __restrict__ bias, const float* __restrict__ resv,
    void* __restrict__ Cv, int M, int N, int K,
    long sA, long sB, long sC, long sR) {
  __shared__ __align__(16) char lds[98304];   // 3 x (A 16K + B 16K)
  const int t = threadIdx.x, lane = t & 63, wid = t >> 6;
  const int wr = wid >> 2, wc = wid & 3;
  const int l15 = lane & 15, g = lane >> 4;
  int m0, n0, z;
  if (ZMODE == 1) {
    int bid = blockIdx.x; z = bid & 7; int r = bid >> 3;
    m0 = (r >> 1) * 256; n0 = (r & 1) * 256;
  } else if (ZMODE == 3) {
    int bid = blockIdx.x; z = bid & 7; int r = bid >> 3;
    m0 = (r >> 2) * 256; n0 = (r & 3) * 256;
  } else {
    m0 = blockIdx.x * 256; n0 = blockIdx.y * 256; z = blockIdx.z;
  }
  const unsigned short* Ab = A + (size_t)z * sA;
  const unsigned short* Bb = B + (size_t)z * sB;

  const f32x4 fz = {0.f, 0.f, 0.f, 0.f};
  f32x4 acc[8][4];
#pragma unroll
  for (int i = 0; i < 8; i++)
#pragma unroll
    for (int j = 0; j < 4; j++) acc[i][j] = fz;

  // per-lane inverse map for staging: LDS byte p -> logical (row, colbyte)
  int rS[2], cS[2];
#pragma unroll
  for (int u = 0; u < 2; u++) {
    int p = u * 8192 + wid * 1024 + lane * 16;
    int L = p >> 7;
    int q = (p & 127) ^ ((L & 7) << 4);
    rS[u] = 2 * L + (q >> 6);
    cS[u] = q & 63;
  }

  auto stageA = [&](int kk, int buf, int u) {
    gld16((const char*)Ab + ((size_t)(m0 + rS[u]) * K + kk) * 2 + cS[u],
          lds + buf * 32768 + u * 8192 + wid * 1024);
  };
  auto stageB = [&](int kk, int buf, int u) {
    gld16((const char*)Bb + ((size_t)(n0 + rS[u]) * K + kk) * 2 + cS[u],
          lds + buf * 32768 + 16384 + u * 8192 + wid * 1024);
  };

  auto ldso = [&](int r, int gg) -> unsigned {
    unsigned L = (unsigned)(r >> 1);
    return L * 128 + ((((unsigned)(r & 1)) * 64 + (unsigned)gg * 16) ^ ((L & 7) << 4));
  };

  const int NT = K >> 5;
#pragma unroll
  for (int u = 0; u < 2; u++) { stageA(0, 0, u); }
#pragma unroll
  for (int u = 0; u < 2; u++) { stageB(0, 0, u); }
#pragma unroll
  for (int u = 0; u < 2; u++) { stageA(32, 1, u); }
#pragma unroll
  for (int u = 0; u < 2; u++) { stageB(32, 1, u); }

  for (int tt = 0; tt < NT; tt++) {
    if (tt + 1 < NT) { asm volatile("s_waitcnt vmcnt(4)" ::: "memory"); }
    else             { asm volatile("s_waitcnt vmcnt(0)" ::: "memory"); }
    __builtin_amdgcn_s_barrier();
    const char* As = lds + (tt % 3) * 32768;
    const char* Bs = As + 16384;
    const int kk2 = (tt + 2) << 5;
    const bool st = kk2 < K;
    const int bn = (tt + 2) % 3;

    short8 bfr[4];
#pragma unroll
    for (int p = 0; p < 2; p++) {
      short8 af[4];
#pragma unroll
      for (int fi = 0; fi < 4; fi++) {
        int r = wr * 128 + (p * 4 + fi) * 16 + l15;
        af[fi] = *(const short8*)(As + ldso(r, g));
      }
      if (p == 0) {
#pragma unroll
        for (int fj = 0; fj < 4; fj++) {
          int r = wc * 64 + fj * 16 + l15;
          bfr[fj] = *(const short8*)(Bs + ldso(r, g));
        }
        if (st) { stageA(kk2, bn, 0); stageA(kk2, bn, 1); }
      } else {
        if (st) { stageB(kk2, bn, 0); stageB(kk2, bn, 1); }
      }
      asm volatile("s_waitcnt lgkmcnt(0)" ::: "memory");
      __builtin_amdgcn_s_setprio(1);
#pragma unroll
      for (int fi = 0; fi < 4; fi++)
#pragma unroll
        for (int fj = 0; fj < 4; fj++)
          acc[p * 4 + fi][fj] =
              __builtin_amdgcn_mfma_f32_16x16x32_bf16(af[fi], bfr[fj], acc[p * 4 + fi][fj], 0, 0, 0);
      __builtin_amdgcn_s_setprio(0);
      __builtin_amdgcn_s_barrier();
    }
  }

  const float* res = RES ? (resv + (size_t)z * sR) : nullptr;
  char* Cb = (char*)Cv + (size_t)z * sC * (OUT_BF16 ? 2 : 4);
#pragma unroll
  for (int i = 0; i < 8; i++) {
#pragma unroll
    for (int jj = 0; jj < 4; jj++) {
      int row = m0 + wr * 128 + i * 16 + g * 4 + jj;
#pragma unroll
      for (int j = 0; j < 4; j++) {
        int col = n0 + wc * 64 + j * 16 + l15;
        float v = acc[i][j][jj];
        if (BIAS_MODE == 1) v += bias[col];
        if (BIAS_MODE == 2) v += bias[row];
        if (RES) v += res[(size_t)row * N + col];
        if (OUT_BF16) ((unsigned short*)Cb)[(size_t)row * N + col] = f2bf(v);
        else          ((float*)Cb)[(size_t)row * N + col] = v;
      }
    }
  }
}

// ---------------- streaming softmax, in place on S bf16 [32768][1024] -----------
// (R5-proven) one wave per row; scale folded in; exact softmax in f32.
__global__ __launch_bounds__(256, 8) void k_softmax(unsigned short* __restrict__ S) {
  const int lane = threadIdx.x & 63;
  const int w = threadIdx.x >> 6;
  const float scale = 0.044194173824159216f;  // 512^-0.5
  for (int r = blockIdx.x * 4 + w; r < 32768; r += gridDim.x * 4) {
    unsigned short* p = S + (size_t)r * 1024 + lane * 16;
    short8 a = *(const short8*)p;
    short8 b = *(const short8*)(p + 8);
    float v[16];
#pragma unroll
    for (int i = 0; i < 8; i++) v[i] = bf2f((unsigned short)a[i]) * scale;
#pragma unroll
    for (int i = 0; i < 8; i++) v[8 + i] = bf2f((unsigned short)b[i]) * scale;
    float m = v[0];
#pragma unroll
    for (int i = 1; i < 16; i++) m = fmaxf(m, v[i]);
#pragma unroll
    for (int d = 1; d < 64; d <<= 1) m = fmaxf(m, __shfl_xor(m, d, 64));
    float s = 0.f;
#pragma unroll
    for (int i = 0; i < 16; i++) { v[i] = __expf(v[i] - m); s += v[i]; }
#pragma unroll
    for (int d = 1; d < 64; d <<= 1) s += __shfl_xor(s, d, 64);
    float inv = 1.0f / s;
    unsigned short tmp[16] __attribute__((aligned(16)));
#pragma unroll
    for (int i = 0; i < 16; i++) tmp[i] = f2bf(v[i] * inv);
    *(i32x4*)p = *(const i32x4*)tmp;
    *(i32x4*)(p + 8) = *(const i32x4*)(tmp + 8);
  }
}

// ---------------- launch ----------------
extern "C" void kernel_launch(void* const* d_in, const int* in_sizes, int n_in,
                              void* d_out, int out_size, void* d_ws, size_t ws_size,
                              hipStream_t stream) {
  (void)in_sizes; (void)n_in; (void)out_size; (void)ws_size;
  const float* x   = (const float*)d_in[0];
  const float* ctx = (const float*)d_in[1];
  const float* Wq  = (const float*)d_in[2];
  const float* bq  = (const float*)d_in[3];
  const float* Wk  = (const float*)d_in[4];
  const float* bk  = (const float*)d_in[5];
  const float* Wv  = (const float*)d_in[6];
  const float* bv  = (const float*)d_in[7];
  const float* Wo  = (const float*)d_in[8];
  const float* bo  = (const float*)d_in[9];
  float* out = (float*)d_out;

  char* ws = (char*)d_ws;
  unsigned short* qb   = (unsigned short*)(ws);              // 33,554,432
  unsigned short* kbuf = (unsigned short*)(ws + 33554432);   //  8,388,608
  unsigned short* vT   = (unsigned short*)(ws + 41943040);   //  8,388,608
  unsigned short* ctxb = (unsigned short*)(ws + 50331648);   // 33,554,432
  unsigned short* WqT  = (unsigned short*)(ws + 83886080);   //    524,288
  unsigned short* WkT  = (unsigned short*)(ws + 84410368);   //    786,432
  unsigned short* WvT  = (unsigned short*)(ws + 85196800);   //    786,432
  unsigned short* WoT  = (unsigned short*)(ws + 85983232);   //    524,288 -> 86,507,520
  // Sbuf overlays xb+cb (both dead by S-GEMM time) - R5-proven layout
  unsigned short* Sbuf = (unsigned short*)(ws + 86507520);   // 67,108,864 -> 153,616,384
  unsigned short* xb   = (unsigned short*)(ws + 86507520);   // 33,554,432
  unsigned short* cb   = (unsigned short*)(ws + 120061952);  // 12,582,912

  dim3 tb(32, 8);
  k_transpose<<<dim3(16, 16), tb, 0, stream>>>(Wq, WqT, 512, 512);
  k_transpose<<<dim3(24, 16), tb, 0, stream>>>(Wk, WkT, 768, 512);
  k_transpose<<<dim3(24, 16), tb, 0, stream>>>(Wv, WvT, 768, 512);
  k_transpose<<<dim3(16, 16), tb, 0, stream>>>(Wo, WoT, 512, 512);

  k_cast<<<dim3(2048), 256, 0, stream>>>(x,   xb, 2097152);
  k_cast<<<dim3(2048), 256, 0, stream>>>(ctx, cb,  786432);

  // q = x @ Wq + bq -> bf16 [32768][512]
  k_gemm3<1, false, true, 0><<<dim3(128, 2, 1), 512, 0, stream>>>(
      xb, WqT, bq, nullptr, qb, 32768, 512, 512, 0, 0, 0, 0);
  // k = ctx @ Wk + bk -> bf16 [8192][512]
  k_gemm<1, false, true, 0><<<dim3(64, 4, 1), 256, 0, stream>>>(
      cb, WkT, bk, nullptr, kbuf, 8192, 512, 768, 0, 0, 0, 0);
  // vT[b] = (ctx[b] @ Wv + bv)^T -> bf16 [8][512][1024]  (z->XCD affinity)
  k_gemm<2, false, true, 2><<<dim3(256), 256, 0, stream>>>(
      WvT, cb, bv, nullptr, vT, 512, 1024, 768, 0, (long)1024 * 768, (long)512 * 1024, 0);
  // S[b] = q[b] @ k[b]^T -> bf16 [8][4096][1024]  (z->XCD affinity; scale in softmax)
  k_gemm3<0, false, true, 3><<<dim3(512), 512, 0, stream>>>(
      qb, kbuf, nullptr, nullptr, Sbuf, 4096, 1024, 512,
      (long)4096 * 512, (long)1024 * 512, (long)4096 * 1024, 0);
  // P^ = softmax(S * scale), in place
  k_softmax<<<dim3(4096), 256, 0, stream>>>(Sbuf);
  // ctx_out[b] = P^[b] @ vT[b]^T -> bf16 [8][4096][512]  (z->XCD affinity)
  k_gemm3<0, false, true, 1><<<dim3(256), 512, 0, stream>>>(
      Sbuf, vT, nullptr, nullptr, ctxb, 4096, 512, 1024,
      (long)4096 * 1024, (long)512 * 1024, (long)4096 * 512, 0);
  // out = ctx_out @ Wo + bo + x -> f32
  k_gemm3<1, true, false, 0><<<dim3(128, 2, 1), 512, 0, stream>>>(
      ctxb, WoT, bo, x, out, 32768, 512, 512, 0, 0, 0, 0);
}

// Round 12
// 217.397 us; speedup vs baseline: 1.1592x; 1.0637x over previous
//
#include <hip/hip_runtime.h>

typedef __attribute__((ext_vector_type(8))) short short8;
typedef __attribute__((ext_vector_type(4))) float f32x4;
typedef __attribute__((ext_vector_type(4))) int i32x4;

#define NSEQ 4096
#define MSEQ 1024
#define HID  512
#define CTXD 768

static __device__ __forceinline__ unsigned short f2bf(float f) {
  union { float f; unsigned u; } v; v.f = f;
  return (unsigned short)((v.u + 0x7fffu + ((v.u >> 16) & 1u)) >> 16);
}
static __device__ __forceinline__ float bf2f(unsigned short u) {
  union { unsigned u; float f; } v; v.u = ((unsigned)u) << 16;
  return v.f;
}

static __device__ __forceinline__ void gld16(const void* g, void* l) {
  __builtin_amdgcn_global_load_lds((const __attribute__((address_space(1))) void*)g,
                                   (__attribute__((address_space(3))) void*)l, 16, 0, 0);
}

// ---------------- weight transpose: W[K][N] f32 -> WT[N][K] bf16 ----------------
__global__ void k_transpose(const float* __restrict__ W, unsigned short* __restrict__ WT,
                            int K, int N) {
  __shared__ float tile[32][33];
  int k0 = blockIdx.x * 32, n0 = blockIdx.y * 32;
  int tx = threadIdx.x, ty = threadIdx.y;
#pragma unroll
  for (int i = 0; i < 32; i += 8)
    tile[ty + i][tx] = W[(size_t)(k0 + ty + i) * N + n0 + tx];
  __syncthreads();
#pragma unroll
  for (int i = 0; i < 32; i += 8)
    WT[(size_t)(n0 + ty + i) * K + k0 + tx] = f2bf(tile[tx][ty + i]);
}

// ---------------- f32 -> bf16 cast, vectorized ----------------
__global__ void k_cast(const float* __restrict__ in, unsigned short* __restrict__ out, int n8) {
  int i = blockIdx.x * blockDim.x + threadIdx.x;
  int stride = gridDim.x * blockDim.x;
  for (; i < n8; i += stride) {
    f32x4 v0 = *(const f32x4*)(in + (size_t)i * 8);
    f32x4 v1 = *(const f32x4*)(in + (size_t)i * 8 + 4);
    unsigned short tmp[8] __attribute__((aligned(16)));
    tmp[0] = f2bf(v0[0]); tmp[1] = f2bf(v0[1]); tmp[2] = f2bf(v0[2]); tmp[3] = f2bf(v0[3]);
    tmp[4] = f2bf(v1[0]); tmp[5] = f2bf(v1[1]); tmp[6] = f2bf(v1[2]); tmp[7] = f2bf(v1[3]);
    *(i32x4*)(out + (size_t)i * 8) = *(const i32x4*)tmp;
  }
}

// ---------------- GEMM 128x128 (R2-proven): C = A[M][K] * BT[N][K]^T ------------
// ZMODE 0: grid (mx,ny,nz). ZMODE 2: flat grid, z=bid&7, r=bid>>3, m=r>>3, n=r&7.
template<int BIAS_MODE, bool RES, bool OUT_BF16, int ZMODE>
__global__ __launch_bounds__(256, 2) void k_gemm(
    const unsigned short* __restrict__ A, const unsigned short* __restrict__ B,
    const float* __restrict__ bias, const float* __restrict__ resv,
    void* __restrict__ Cv, int M, int N, int K,
    long sA, long sB, long sC, long sR) {
  __shared__ __align__(16) char lds[65536];
  const int t = threadIdx.x, lane = t & 63, wid = t >> 6;
  const int wr = wid >> 1, wc = wid & 1;
  int m0, n0, z;
  if (ZMODE == 2) {
    int bid = blockIdx.x; z = bid & 7; int r = bid >> 3;
    m0 = (r >> 3) * 128; n0 = (r & 7) * 128;
  } else {
    m0 = blockIdx.x * 128; n0 = blockIdx.y * 128; z = blockIdx.z;
  }
  const unsigned short* Ab = A + (size_t)z * sA;
  const unsigned short* Bb = B + (size_t)z * sB;

  const f32x4 fz = {0.f, 0.f, 0.f, 0.f};
  f32x4 acc[4][4];
#pragma unroll
  for (int i = 0; i < 4; i++)
#pragma unroll
    for (int j = 0; j < 4; j++) acc[i][j] = fz;

  const int srow = t >> 3;      // 0..31
  const int schunk = t & 7;

  auto stage = [&](int kk, int buf) {
    const char* a8 = (const char*)Ab;
    const char* b8 = (const char*)Bb;
#pragma unroll
    for (int i = 0; i < 4; i++) {
      int row = i * 32 + srow;
      gld16(a8 + ((size_t)(m0 + row) * K + kk) * 2 + ((schunk ^ (row & 7)) << 4),
            lds + buf * 32768 + i * 4096 + wid * 1024);
    }
#pragma unroll
    for (int i = 0; i < 4; i++) {
      int row = i * 32 + srow;
      gld16(b8 + ((size_t)(n0 + row) * K + kk) * 2 + ((schunk ^ (row & 7)) << 4),
            lds + buf * 32768 + 16384 + i * 4096 + wid * 1024);
    }
  };

  stage(0, 0);
  int buf = 0;
  for (int kk = 0; kk < K; kk += 64) {
    if (kk + 64 < K) {
      stage(kk + 64, buf ^ 1);
      asm volatile("s_waitcnt vmcnt(8)" ::: "memory");
    } else {
      asm volatile("s_waitcnt vmcnt(0)" ::: "memory");
    }
    __builtin_amdgcn_s_barrier();
    const char* As = lds + buf * 32768;
    const char* Bs = As + 16384;
#pragma unroll
    for (int ks = 0; ks < 2; ks++) {
      short8 af[4], bfr[4];
#pragma unroll
      for (int i = 0; i < 4; i++) {
        int r = wr * 64 + i * 16 + (lane & 15);
        af[i] = *(const short8*)(As + r * 128 +
                 (((unsigned)(ks * 64 + (lane >> 4) * 16)) ^ ((unsigned)(r & 7) << 4)));
      }
#pragma unroll
      for (int i = 0; i < 4; i++) {
        int r = wc * 64 + i * 16 + (lane & 15);
        bfr[i] = *(const short8*)(Bs + r * 128 +
                 (((unsigned)(ks * 64 + (lane >> 4) * 16)) ^ ((unsigned)(r & 7) << 4)));
      }
#pragma unroll
      for (int i = 0; i < 4; i++)
#pragma unroll
        for (int j = 0; j < 4; j++)
          acc[i][j] = __builtin_amdgcn_mfma_f32_16x16x32_bf16(af[i], bfr[j], acc[i][j], 0, 0, 0);
    }
    asm volatile("s_waitcnt lgkmcnt(0)" ::: "memory");
    __builtin_amdgcn_s_barrier();
    buf ^= 1;
  }

  const float* res = RES ? (resv + (size_t)z * sR) : nullptr;
  char* Cb = (char*)Cv + (size_t)z * sC * (OUT_BF16 ? 2 : 4);
#pragma unroll
  for (int i = 0; i < 4; i++) {
#pragma unroll
    for (int jj = 0; jj < 4; jj++) {
      int row = m0 + wr * 64 + i * 16 + (lane >> 4) * 4 + jj;
#pragma unroll
      for (int j = 0; j < 4; j++) {
        int col = n0 + wc * 64 + j * 16 + (lane & 15);
        float v = acc[i][j][jj];
        if (BIAS_MODE == 1) v += bias[col];
        if (BIAS_MODE == 2) v += bias[row];
        if (RES) v += res[(size_t)row * N + col];
        if (OUT_BF16) ((unsigned short*)Cb)[(size_t)row * N + col] = f2bf(v);
        else          ((float*)Cb)[(size_t)row * N + col] = v;
      }
    }
  }
}

// ---------------- GEMM 256x256, BK=32, 8 waves (2x4), 3-buffer ring -------------
// ZMODE 0: grid (mx,ny,nz). ZMODE 1: flat, z=bid&7, r=bid>>3, m=r>>1, n=r&1.
// ZMODE 3: flat, z=bid&7, r=bid>>3, m=r>>2, n=r&3.
// EPI 0: bias/res epilogue. EPI 1: store bf16(exp(acc*scale)) + per-block
// partial row-sums into psout[4][B*4096] (deterministic, no atomics).
// EPI 2: multiply by 1/(sum of 4 partials) before bf16 store (PV normalize).
template<int BIAS_MODE, bool RES, bool OUT_BF16, int ZMODE, int EPI>
__global__ __launch_bounds__(512, 1) void k_gemm3(
    const unsigned short* __restrict__ A, const unsigned short* __restrict__ B,
    const float* __restrict__ bias, const float* __restrict__ resv,
    void* __restrict__ Cv, int M, int N, int K,
    long sA, long sB, long sC, long sR,
    const float* __restrict__ ps, float* __restrict__ psout) {
  __shared__ __align__(16) char lds[98304];   // 3 x (A 16K + B 16K)
  const int t = threadIdx.x, lane = t & 63, wid = t >> 6;
  const int wr = wid >> 2, wc = wid & 3;
  const int l15 = lane & 15, g = lane >> 4;
  int m0, n0, z;
  if (ZMODE == 1) {
    int bid = blockIdx.x; z = bid & 7; int r = bid >> 3;
    m0 = (r >> 1) * 256; n0 = (r & 1) * 256;
  } else if (ZMODE == 3) {
    int bid = blockIdx.x; z = bid & 7; int r = bid >> 3;
    m0 = (r >> 2) * 256; n0 = (r & 3) * 256;
  } else {
    m0 = blockIdx.x * 256; n0 = blockIdx.y * 256; z = blockIdx.z;
  }
  const unsigned short* Ab = A + (size_t)z * sA;
  const unsigned short* Bb = B + (size_t)z * sB;

  const f32x4 fz = {0.f, 0.f, 0.f, 0.f};
  f32x4 acc[8][4];
#pragma unroll
  for (int i = 0; i < 8; i++)
#pragma unroll
    for (int j = 0; j < 4; j++) acc[i][j] = fz;

  // per-lane inverse map for staging: LDS byte p -> logical (row, colbyte)
  int rS[2], cS[2];
#pragma unroll
  for (int u = 0; u < 2; u++) {
    int p = u * 8192 + wid * 1024 + lane * 16;
    int L = p >> 7;
    int q = (p & 127) ^ ((L & 7) << 4);
    rS[u] = 2 * L + (q >> 6);
    cS[u] = q & 63;
  }

  auto stageA = [&](int kk, int buf, int u) {
    gld16((const char*)Ab + ((size_t)(m0 + rS[u]) * K + kk) * 2 + cS[u],
          lds + buf * 32768 + u * 8192 + wid * 1024);
  };
  auto stageB = [&](int kk, int buf, int u) {
    gld16((const char*)Bb + ((size_t)(n0 + rS[u]) * K + kk) * 2 + cS[u],
          lds + buf * 32768 + 16384 + u * 8192 + wid * 1024);
  };

  auto ldso = [&](int r, int gg) -> unsigned {
    unsigned L = (unsigned)(r >> 1);
    return L * 128 + ((((unsigned)(r & 1)) * 64 + (unsigned)gg * 16) ^ ((L & 7) << 4));
  };

  const int NT = K >> 5;
#pragma unroll
  for (int u = 0; u < 2; u++) { stageA(0, 0, u); }
#pragma unroll
  for (int u = 0; u < 2; u++) { stageB(0, 0, u); }
#pragma unroll
  for (int u = 0; u < 2; u++) { stageA(32, 1, u); }
#pragma unroll
  for (int u = 0; u < 2; u++) { stageB(32, 1, u); }

  for (int tt = 0; tt < NT; tt++) {
    if (tt + 1 < NT) { asm volatile("s_waitcnt vmcnt(4)" ::: "memory"); }
    else             { asm volatile("s_waitcnt vmcnt(0)" ::: "memory"); }
    __builtin_amdgcn_s_barrier();
    const char* As = lds + (tt % 3) * 32768;
    const char* Bs = As + 16384;
    const int kk2 = (tt + 2) << 5;
    const bool st = kk2 < K;
    const int bn = (tt + 2) % 3;

    short8 bfr[4];
#pragma unroll
    for (int p = 0; p < 2; p++) {
      short8 af[4];
#pragma unroll
      for (int fi = 0; fi < 4; fi++) {
        int r = wr * 128 + (p * 4 + fi) * 16 + l15;
        af[fi] = *(const short8*)(As + ldso(r, g));
      }
      if (p == 0) {
#pragma unroll
        for (int fj = 0; fj < 4; fj++) {
          int r = wc * 64 + fj * 16 + l15;
          bfr[fj] = *(const short8*)(Bs + ldso(r, g));
        }
        if (st) { stageA(kk2, bn, 0); stageA(kk2, bn, 1); }
      } else {
        if (st) { stageB(kk2, bn, 0); stageB(kk2, bn, 1); }
      }
      asm volatile("s_waitcnt lgkmcnt(0)" ::: "memory");
      __builtin_amdgcn_s_setprio(1);
#pragma unroll
      for (int fi = 0; fi < 4; fi++)
#pragma unroll
        for (int fj = 0; fj < 4; fj++)
          acc[p * 4 + fi][fj] =
              __builtin_amdgcn_mfma_f32_16x16x32_bf16(af[fi], bfr[fj], acc[p * 4 + fi][fj], 0, 0, 0);
      __builtin_amdgcn_s_setprio(0);
      __builtin_amdgcn_s_barrier();
    }
  }

  char* Cb = (char*)Cv + (size_t)z * sC * (OUT_BF16 ? 2 : 4);

  if (EPI == 1) {
    // exp epilogue: store bf16(exp(acc*scale)); deterministic partial row-sums.
    const float scale = 0.044194173824159216f;  // 512^-0.5
    float* redb = (float*)lds;                  // [4][256] (ring is dead)
#pragma unroll
    for (int i = 0; i < 8; i++) {
#pragma unroll
      for (int jj = 0; jj < 4; jj++) {
        int rl = wr * 128 + i * 16 + g * 4 + jj;   // row within tile
        int row = m0 + rl;
        float e4 = 0.f;
#pragma unroll
        for (int j = 0; j < 4; j++) {
          int col = n0 + wc * 64 + j * 16 + l15;
          float e = __expf(acc[i][j][jj] * scale);
          unsigned short h = f2bf(e);
          ((unsigned short*)Cb)[(size_t)row * N + col] = h;
          e4 += bf2f(h);
        }
#pragma unroll
        for (int d = 1; d < 16; d <<= 1) e4 += __shfl_xor(e4, d, 64);
        if (l15 == 0) redb[wc * 256 + rl] = e4;
      }
    }
    __syncthreads();
    if (t < 256) {
      float s4 = redb[t] + redb[256 + t] + redb[512 + t] + redb[768 + t];
      psout[(size_t)(n0 >> 8) * 32768 + (size_t)z * 4096 + (m0 + t)] = s4;
    }
    return;
  }

  const float* res = RES ? (resv + (size_t)z * sR) : nullptr;
#pragma unroll
  for (int i = 0; i < 8; i++) {
#pragma unroll
    for (int jj = 0; jj < 4; jj++) {
      int row = m0 + wr * 128 + i * 16 + g * 4 + jj;
      float inv = 1.0f;
      if (EPI == 2) {
        size_t r = (size_t)z * 4096 + row;
        inv = 1.0f / (ps[r] + ps[32768 + r] + ps[65536 + r] + ps[98304 + r]);
      }
#pragma unroll
      for (int j = 0; j < 4; j++) {
        int col = n0 + wc * 64 + j * 16 + l15;
        float v = acc[i][j][jj];
        if (EPI == 2) v *= inv;
        if (BIAS_MODE == 1) v += bias[col];
        if (BIAS_MODE == 2) v += bias[row];
        if (RES) v += res[(size_t)row * N + col];
        if (OUT_BF16) ((unsigned short*)Cb)[(size_t)row * N + col] = f2bf(v);
        else          ((float*)Cb)[(size_t)row * N + col] = v;
      }
    }
  }
}

// ---------------- launch ----------------
extern "C" void kernel_launch(void* const* d_in, const int* in_sizes, int n_in,
                              void* d_out, int out_size, void* d_ws, size_t ws_size,
                              hipStream_t stream) {
  (void)in_sizes; (void)n_in; (void)out_size; (void)ws_size;
  const float* x   = (const float*)d_in[0];
  const float* ctx = (const float*)d_in[1];
  const float* Wq  = (const float*)d_in[2];
  const float* bq  = (const float*)d_in[3];
  const float* Wk  = (const float*)d_in[4];
  const float* bk  = (const float*)d_in[5];
  const float* Wv  = (const float*)d_in[6];
  const float* bv  = (const float*)d_in[7];
  const float* Wo  = (const float*)d_in[8];
  const float* bo  = (const float*)d_in[9];
  float* out = (float*)d_out;

  char* ws = (char*)d_ws;
  unsigned short* qb   = (unsigned short*)(ws);              // 33,554,432
  unsigned short* kbuf = (unsigned short*)(ws + 33554432);   //  8,388,608
  unsigned short* vT   = (unsigned short*)(ws + 41943040);   //  8,388,608
  unsigned short* ctxb = (unsigned short*)(ws + 50331648);   // 33,554,432
  unsigned short* WqT  = (unsigned short*)(ws + 83886080);   //    524,288
  unsigned short* WkT  = (unsigned short*)(ws + 84410368);   //    786,432
  unsigned short* WvT  = (unsigned short*)(ws + 85196800);   //    786,432
  unsigned short* WoT  = (unsigned short*)(ws + 85983232);   //    524,288 -> 86,507,520
  // Sbuf overlays xb+cb (both dead by S-GEMM time)
  unsigned short* Sbuf = (unsigned short*)(ws + 86507520);   // 67,108,864 -> 153,616,384
  unsigned short* xb   = (unsigned short*)(ws + 86507520);   // 33,554,432
  unsigned short* cb   = (unsigned short*)(ws + 120061952);  // 12,582,912
  float* psums = (float*)(ws + 153616384);                   // 4*32768*4 = 524,288

  dim3 tb(32, 8);
  k_transpose<<<dim3(16, 16), tb, 0, stream>>>(Wq, WqT, 512, 512);
  k_transpose<<<dim3(24, 16), tb, 0, stream>>>(Wk, WkT, 768, 512);
  k_transpose<<<dim3(24, 16), tb, 0, stream>>>(Wv, WvT, 768, 512);
  k_transpose<<<dim3(16, 16), tb, 0, stream>>>(Wo, WoT, 512, 512);

  k_cast<<<dim3(2048), 256, 0, stream>>>(x,   xb, 2097152);
  k_cast<<<dim3(2048), 256, 0, stream>>>(ctx, cb,  786432);

  // q = x @ Wq + bq -> bf16 [32768][512]
  k_gemm3<1, false, true, 0, 0><<<dim3(128, 2, 1), 512, 0, stream>>>(
      xb, WqT, bq, nullptr, qb, 32768, 512, 512, 0, 0, 0, 0, nullptr, nullptr);
  // k = ctx @ Wk + bk -> bf16 [8192][512]
  k_gemm<1, false, true, 0><<<dim3(64, 4, 1), 256, 0, stream>>>(
      cb, WkT, bk, nullptr, kbuf, 8192, 512, 768, 0, 0, 0, 0);
  // vT[b] = (ctx[b] @ Wv + bv)^T -> bf16 [8][512][1024]  (z->XCD affinity)
  k_gemm<2, false, true, 2><<<dim3(256), 256, 0, stream>>>(
      WvT, cb, bv, nullptr, vT, 512, 1024, 768, 0, (long)1024 * 768, (long)512 * 1024, 0);
  // Pexp[b] = exp(q[b] k[b]^T * scale) -> bf16, + partial row-sums (softmax fused)
  k_gemm3<0, false, true, 3, 1><<<dim3(512), 512, 0, stream>>>(
      qb, kbuf, nullptr, nullptr, Sbuf, 4096, 1024, 512,
      (long)4096 * 512, (long)1024 * 512, (long)4096 * 1024, 0, nullptr, psums);
  // ctx_out[b] = (Pexp[b] @ vT[b]^T) / rowsum -> bf16 [8][4096][512]
  k_gemm3<0, false, true, 1, 2><<<dim3(256), 512, 0, stream>>>(
      Sbuf, vT, nullptr, nullptr, ctxb, 4096, 512, 1024,
      (long)4096 * 1024, (long)512 * 1024, (long)4096 * 512, 0, psums, nullptr);
  // out = ctx_out @ Wo + bo + x -> f32
  k_gemm3<1, true, false, 0, 0><<<dim3(128, 2, 1), 512, 0, stream>>>(
      ctxb, WoT, bo, x, out, 32768, 512, 512, 0, 0, 0, 0, nullptr, nullptr);
}

// Round 13
// 214.768 us; speedup vs baseline: 1.1734x; 1.0122x over previous
//
#include <hip/hip_runtime.h>

typedef __attribute__((ext_vector_type(8))) short short8;
typedef __attribute__((ext_vector_type(4))) float f32x4;
typedef __attribute__((ext_vector_type(4))) int i32x4;

#define NSEQ 4096
#define MSEQ 1024
#define HID  512
#define CTXD 768

static __device__ __forceinline__ unsigned short f2bf(float f) {
  union { float f; unsigned u; } v; v.f = f;
  return (unsigned short)((v.u + 0x7fffu + ((v.u >> 16) & 1u)) >> 16);
}
static __device__ __forceinline__ float bf2f(unsigned short u) {
  union { unsigned u; float f; } v; v.u = ((unsigned)u) << 16;
  return v.f;
}

static __device__ __forceinline__ void gld16(const void* g, void* l) {
  __builtin_amdgcn_global_load_lds((const __attribute__((address_space(1))) void*)g,
                                   (__attribute__((address_space(3))) void*)l, 16, 0, 0);
}

// ---------------- weight transpose: W[K][N] f32 -> WT[N][K] bf16 ----------------
__global__ void k_transpose(const float* __restrict__ W, unsigned short* __restrict__ WT,
                            int K, int N) {
  __shared__ float tile[32][33];
  int k0 = blockIdx.x * 32, n0 = blockIdx.y * 32;
  int tx = threadIdx.x, ty = threadIdx.y;
#pragma unroll
  for (int i = 0; i < 32; i += 8)
    tile[ty + i][tx] = W[(size_t)(k0 + ty + i) * N + n0 + tx];
  __syncthreads();
#pragma unroll
  for (int i = 0; i < 32; i += 8)
    WT[(size_t)(n0 + ty + i) * K + k0 + tx] = f2bf(tile[tx][ty + i]);
}

// ---------------- f32 -> bf16 cast, vectorized ----------------
__global__ void k_cast(const float* __restrict__ in, unsigned short* __restrict__ out, int n8) {
  int i = blockIdx.x * blockDim.x + threadIdx.x;
  int stride = gridDim.x * blockDim.x;
  for (; i < n8; i += stride) {
    f32x4 v0 = *(const f32x4*)(in + (size_t)i * 8);
    f32x4 v1 = *(const f32x4*)(in + (size_t)i * 8 + 4);
    unsigned short tmp[8] __attribute__((aligned(16)));
    tmp[0] = f2bf(v0[0]); tmp[1] = f2bf(v0[1]); tmp[2] = f2bf(v0[2]); tmp[3] = f2bf(v0[3]);
    tmp[4] = f2bf(v1[0]); tmp[5] = f2bf(v1[1]); tmp[6] = f2bf(v1[2]); tmp[7] = f2bf(v1[3]);
    *(i32x4*)(out + (size_t)i * 8) = *(const i32x4*)tmp;
  }
}

// ---------------- GEMM 128x128 (R2-proven): C = A[M][K] * BT[N][K]^T ------------
// ZMODE 0: grid (mx,ny,nz). ZMODE 2: flat grid, z=bid&7, r=bid>>3, m=r>>3, n=r&7.
template<int BIAS_MODE, bool RES, bool OUT_BF16, int ZMODE>
__global__ __launch_bounds__(256, 2) void k_gemm(
    const unsigned short* __restrict__ A, const unsigned short* __restrict__ B,
    const float* __restrict__ bias, const float* __restrict__ resv,
    void* __restrict__ Cv, int M, int N, int K,
    long sA, long sB, long sC, long sR) {
  __shared__ __align__(16) char lds[65536];
  const int t = threadIdx.x, lane = t & 63, wid = t >> 6;
  const int wr = wid >> 1, wc = wid & 1;
  int m0, n0, z;
  if (ZMODE == 2) {
    int bid = blockIdx.x; z = bid & 7; int r = bid >> 3;
    m0 = (r >> 3) * 128; n0 = (r & 7) * 128;
  } else {
    m0 = blockIdx.x * 128; n0 = blockIdx.y * 128; z = blockIdx.z;
  }
  const unsigned short* Ab = A + (size_t)z * sA;
  const unsigned short* Bb = B + (size_t)z * sB;

  const f32x4 fz = {0.f, 0.f, 0.f, 0.f};
  f32x4 acc[4][4];
#pragma unroll
  for (int i = 0; i < 4; i++)
#pragma unroll
    for (int j = 0; j < 4; j++) acc[i][j] = fz;

  const int srow = t >> 3;      // 0..31
  const int schunk = t & 7;

  auto stage = [&](int kk, int buf) {
    const char* a8 = (const char*)Ab;
    const char* b8 = (const char*)Bb;
#pragma unroll
    for (int i = 0; i < 4; i++) {
      int row = i * 32 + srow;
      gld16(a8 + ((size_t)(m0 + row) * K + kk) * 2 + ((schunk ^ (row & 7)) << 4),
            lds + buf * 32768 + i * 4096 + wid * 1024);
    }
#pragma unroll
    for (int i = 0; i < 4; i++) {
      int row = i * 32 + srow;
      gld16(b8 + ((size_t)(n0 + row) * K + kk) * 2 + ((schunk ^ (row & 7)) << 4),
            lds + buf * 32768 + 16384 + i * 4096 + wid * 1024);
    }
  };

  stage(0, 0);
  int buf = 0;
  for (int kk = 0; kk < K; kk += 64) {
    if (kk + 64 < K) {
      stage(kk + 64, buf ^ 1);
      asm volatile("s_waitcnt vmcnt(8)" ::: "memory");
    } else {
      asm volatile("s_waitcnt vmcnt(0)" ::: "memory");
    }
    __builtin_amdgcn_s_barrier();
    const char* As = lds + buf * 32768;
    const char* Bs = As + 16384;
#pragma unroll
    for (int ks = 0; ks < 2; ks++) {
      short8 af[4], bfr[4];
#pragma unroll
      for (int i = 0; i < 4; i++) {
        int r = wr * 64 + i * 16 + (lane & 15);
        af[i] = *(const short8*)(As + r * 128 +
                 (((unsigned)(ks * 64 + (lane >> 4) * 16)) ^ ((unsigned)(r & 7) << 4)));
      }
#pragma unroll
      for (int i = 0; i < 4; i++) {
        int r = wc * 64 + i * 16 + (lane & 15);
        bfr[i] = *(const short8*)(Bs + r * 128 +
                 (((unsigned)(ks * 64 + (lane >> 4) * 16)) ^ ((unsigned)(r & 7) << 4)));
      }
#pragma unroll
      for (int i = 0; i < 4; i++)
#pragma unroll
        for (int j = 0; j < 4; j++)
          acc[i][j] = __builtin_amdgcn_mfma_f32_16x16x32_bf16(af[i], bfr[j], acc[i][j], 0, 0, 0);
    }
    asm volatile("s_waitcnt lgkmcnt(0)" ::: "memory");
    __builtin_amdgcn_s_barrier();
    buf ^= 1;
  }

  const float* res = RES ? (resv + (size_t)z * sR) : nullptr;
  char* Cb = (char*)Cv + (size_t)z * sC * (OUT_BF16 ? 2 : 4);
#pragma unroll
  for (int i = 0; i < 4; i++) {
#pragma unroll
    for (int jj = 0; jj < 4; jj++) {
      int row = m0 + wr * 64 + i * 16 + (lane >> 4) * 4 + jj;
#pragma unroll
      for (int j = 0; j < 4; j++) {
        int col = n0 + wc * 64 + j * 16 + (lane & 15);
        float v = acc[i][j][jj];
        if (BIAS_MODE == 1) v += bias[col];
        if (BIAS_MODE == 2) v += bias[row];
        if (RES) v += res[(size_t)row * N + col];
        if (OUT_BF16) ((unsigned short*)Cb)[(size_t)row * N + col] = f2bf(v);
        else          ((float*)Cb)[(size_t)row * N + col] = v;
      }
    }
  }
}

// ---------------- GEMM 256x256, BK=32, 8 waves (2x4), 3-buffer ring -------------
// Single-phase K-loop, ONE barrier per tile (slot-liveness: region tt reads
// slot tt%3, writes slot (tt+2)%3; reads of slot (tt-1)%3 are drained by each
// wave's lgkmcnt(0) before it reaches barrier(tt)).
// ZMODE 0: grid (mx,ny,nz). ZMODE 1: flat, z=bid&7, r=bid>>3, m=r>>1, n=r&1.
// ZMODE 3: flat, z=bid&7, r=bid>>3, m=r>>2, n=r&3.
// EPI 0: bias/res. EPI 1: bf16(exp(acc*scale)) + deterministic partial row-sums.
// EPI 2: multiply by 1/(sum of 4 partials) before store (PV normalize).
template<int BIAS_MODE, bool RES, bool OUT_BF16, int ZMODE, int EPI>
__global__ __launch_bounds__(512, 1) void k_gemm3(
    const unsigned short* __restrict__ A, const unsigned short* __restrict__ B,
    const float* __restrict__ bias, const float* __restrict__ resv,
    void* __restrict__ Cv, int M, int N, int K,
    long sA, long sB, long sC, long sR,
    const float* __restrict__ ps, float* __restrict__ psout) {
  __shared__ __align__(16) char lds[98304];   // 3 x (A 16K + B 16K)
  const int t = threadIdx.x, lane = t & 63, wid = t >> 6;
  const int wr = wid >> 2, wc = wid & 3;
  const int l15 = lane & 15, g = lane >> 4;
  int m0, n0, z;
  if (ZMODE == 1) {
    int bid = blockIdx.x; z = bid & 7; int r = bid >> 3;
    m0 = (r >> 1) * 256; n0 = (r & 1) * 256;
  } else if (ZMODE == 3) {
    int bid = blockIdx.x; z = bid & 7; int r = bid >> 3;
    m0 = (r >> 2) * 256; n0 = (r & 3) * 256;
  } else {
    m0 = blockIdx.x * 256; n0 = blockIdx.y * 256; z = blockIdx.z;
  }
  const unsigned short* Ab = A + (size_t)z * sA;
  const unsigned short* Bb = B + (size_t)z * sB;

  const f32x4 fz = {0.f, 0.f, 0.f, 0.f};
  f32x4 acc[8][4];
#pragma unroll
  for (int i = 0; i < 8; i++)
#pragma unroll
    for (int j = 0; j < 4; j++) acc[i][j] = fz;

  // per-lane inverse map for staging: LDS byte p -> logical (row, colbyte)
  int rS[2], cS[2];
#pragma unroll
  for (int u = 0; u < 2; u++) {
    int p = u * 8192 + wid * 1024 + lane * 16;
    int L = p >> 7;
    int q = (p & 127) ^ ((L & 7) << 4);
    rS[u] = 2 * L + (q >> 6);
    cS[u] = q & 63;
  }

  auto stageA = [&](int kk, int buf, int u) {
    gld16((const char*)Ab + ((size_t)(m0 + rS[u]) * K + kk) * 2 + cS[u],
          lds + buf * 32768 + u * 8192 + wid * 1024);
  };
  auto stageB = [&](int kk, int buf, int u) {
    gld16((const char*)Bb + ((size_t)(n0 + rS[u]) * K + kk) * 2 + cS[u],
          lds + buf * 32768 + 16384 + u * 8192 + wid * 1024);
  };

  auto ldso = [&](int r, int gg) -> unsigned {
    unsigned L = (unsigned)(r >> 1);
    return L * 128 + ((((unsigned)(r & 1)) * 64 + (unsigned)gg * 16) ^ ((L & 7) << 4));
  };

  const int NT = K >> 5;
#pragma unroll
  for (int u = 0; u < 2; u++) { stageA(0, 0, u); }
#pragma unroll
  for (int u = 0; u < 2; u++) { stageB(0, 0, u); }
#pragma unroll
  for (int u = 0; u < 2; u++) { stageA(32, 1, u); }
#pragma unroll
  for (int u = 0; u < 2; u++) { stageB(32, 1, u); }

  for (int tt = 0; tt < NT; tt++) {
    if (tt + 1 < NT) { asm volatile("s_waitcnt vmcnt(4)" ::: "memory"); }
    else             { asm volatile("s_waitcnt vmcnt(0)" ::: "memory"); }
    __builtin_amdgcn_s_barrier();
    const char* As = lds + (tt % 3) * 32768;
    const char* Bs = As + 16384;
    const int kk2 = (tt + 2) << 5;
    const bool st = kk2 < K;
    const int bn = (tt + 2) % 3;

    short8 af[8], bfr[4];
#pragma unroll
    for (int fi = 0; fi < 8; fi++) {
      int r = wr * 128 + fi * 16 + l15;
      af[fi] = *(const short8*)(As + ldso(r, g));
    }
#pragma unroll
    for (int fj = 0; fj < 4; fj++) {
      int r = wc * 64 + fj * 16 + l15;
      bfr[fj] = *(const short8*)(Bs + ldso(r, g));
    }
    if (st) { stageA(kk2, bn, 0); stageA(kk2, bn, 1); stageB(kk2, bn, 0); stageB(kk2, bn, 1); }
    asm volatile("s_waitcnt lgkmcnt(0)" ::: "memory");
    __builtin_amdgcn_s_setprio(1);
#pragma unroll
    for (int fi = 0; fi < 8; fi++)
#pragma unroll
      for (int fj = 0; fj < 4; fj++)
        acc[fi][fj] =
            __builtin_amdgcn_mfma_f32_16x16x32_bf16(af[fi], bfr[fj], acc[fi][fj], 0, 0, 0);
    __builtin_amdgcn_s_setprio(0);
  }
  __builtin_amdgcn_s_barrier();   // protect LDS reuse in epilogue (EPI=1 redb)

  char* Cb = (char*)Cv + (size_t)z * sC * (OUT_BF16 ? 2 : 4);

  if (EPI == 1) {
    // exp epilogue: store bf16(exp(acc*scale)); deterministic partial row-sums.
    const float scale = 0.044194173824159216f;  // 512^-0.5
    float* redb = (float*)lds;                  // [4][256] (ring is dead)
#pragma unroll
    for (int i = 0; i < 8; i++) {
#pragma unroll
      for (int jj = 0; jj < 4; jj++) {
        int rl = wr * 128 + i * 16 + g * 4 + jj;   // row within tile
        int row = m0 + rl;
        float e4 = 0.f;
#pragma unroll
        for (int j = 0; j < 4; j++) {
          int col = n0 + wc * 64 + j * 16 + l15;
          float e = __expf(acc[i][j][jj] * scale);
          unsigned short h = f2bf(e);
          ((unsigned short*)Cb)[(size_t)row * N + col] = h;
          e4 += bf2f(h);
        }
#pragma unroll
        for (int d = 1; d < 16; d <<= 1) e4 += __shfl_xor(e4, d, 64);
        if (l15 == 0) redb[wc * 256 + rl] = e4;
      }
    }
    __syncthreads();
    if (t < 256) {
      float s4 = redb[t] + redb[256 + t] + redb[512 + t] + redb[768 + t];
      psout[(size_t)(n0 >> 8) * 32768 + (size_t)z * 4096 + (m0 + t)] = s4;
    }
    return;
  }

  const float* res = RES ? (resv + (size_t)z * sR) : nullptr;
#pragma unroll
  for (int i = 0; i < 8; i++) {
#pragma unroll
    for (int jj = 0; jj < 4; jj++) {
      int row = m0 + wr * 128 + i * 16 + g * 4 + jj;
      float inv = 1.0f;
      if (EPI == 2) {
        size_t r = (size_t)z * 4096 + row;
        inv = 1.0f / (ps[r] + ps[32768 + r] + ps[65536 + r] + ps[98304 + r]);
      }
#pragma unroll
      for (int j = 0; j < 4; j++) {
        int col = n0 + wc * 64 + j * 16 + l15;
        float v = acc[i][j][jj];
        if (EPI == 2) v *= inv;
        if (BIAS_MODE == 1) v += bias[col];
        if (BIAS_MODE == 2) v += bias[row];
        if (RES) v += res[(size_t)row * N + col];
        if (OUT_BF16) ((unsigned short*)Cb)[(size_t)row * N + col] = f2bf(v);
        else          ((float*)Cb)[(size_t)row * N + col] = v;
      }
    }
  }
}

// ---------------- launch ----------------
extern "C" void kernel_launch(void* const* d_in, const int* in_sizes, int n_in,
                              void* d_out, int out_size, void* d_ws, size_t ws_size,
                              hipStream_t stream) {
  (void)in_sizes; (void)n_in; (void)out_size; (void)ws_size;
  const float* x   = (const float*)d_in[0];
  const float* ctx = (const float*)d_in[1];
  const float* Wq  = (const float*)d_in[2];
  const float* bq  = (const float*)d_in[3];
  const float* Wk  = (const float*)d_in[4];
  const float* bk  = (const float*)d_in[5];
  const float* Wv  = (const float*)d_in[6];
  const float* bv  = (const float*)d_in[7];
  const float* Wo  = (const float*)d_in[8];
  const float* bo  = (const float*)d_in[9];
  float* out = (float*)d_out;

  char* ws = (char*)d_ws;
  unsigned short* qb   = (unsigned short*)(ws);              // 33,554,432
  unsigned short* kbuf = (unsigned short*)(ws + 33554432);   //  8,388,608
  unsigned short* vT   = (unsigned short*)(ws + 41943040);   //  8,388,608
  unsigned short* ctxb = (unsigned short*)(ws + 50331648);   // 33,554,432
  unsigned short* WqT  = (unsigned short*)(ws + 83886080);   //    524,288
  unsigned short* WkT  = (unsigned short*)(ws + 84410368);   //    786,432
  unsigned short* WvT  = (unsigned short*)(ws + 85196800);   //    786,432
  unsigned short* WoT  = (unsigned short*)(ws + 85983232);   //    524,288 -> 86,507,520
  // Sbuf overlays xb+cb (both dead by S-GEMM time)
  unsigned short* Sbuf = (unsigned short*)(ws + 86507520);   // 67,108,864 -> 153,616,384
  unsigned short* xb   = (unsigned short*)(ws + 86507520);   // 33,554,432
  unsigned short* cb   = (unsigned short*)(ws + 120061952);  // 12,582,912
  float* psums = (float*)(ws + 153616384);                   // 4*32768*4 = 524,288

  dim3 tb(32, 8);
  k_transpose<<<dim3(16, 16), tb, 0, stream>>>(Wq, WqT, 512, 512);
  k_transpose<<<dim3(24, 16), tb, 0, stream>>>(Wk, WkT, 768, 512);
  k_transpose<<<dim3(24, 16), tb, 0, stream>>>(Wv, WvT, 768, 512);
  k_transpose<<<dim3(16, 16), tb, 0, stream>>>(Wo, WoT, 512, 512);

  k_cast<<<dim3(2048), 256, 0, stream>>>(x,   xb, 2097152);
  k_cast<<<dim3(2048), 256, 0, stream>>>(ctx, cb,  786432);

  // q = x @ Wq + bq -> bf16 [32768][512]
  k_gemm3<1, false, true, 0, 0><<<dim3(128, 2, 1), 512, 0, stream>>>(
      xb, WqT, bq, nullptr, qb, 32768, 512, 512, 0, 0, 0, 0, nullptr, nullptr);
  // k = ctx @ Wk + bk -> bf16 [8192][512]
  k_gemm<1, false, true, 0><<<dim3(64, 4, 1), 256, 0, stream>>>(
      cb, WkT, bk, nullptr, kbuf, 8192, 512, 768, 0, 0, 0, 0);
  // vT[b] = (ctx[b] @ Wv + bv)^T -> bf16 [8][512][1024]  (z->XCD affinity)
  k_gemm<2, false, true, 2><<<dim3(256), 256, 0, stream>>>(
      WvT, cb, bv, nullptr, vT, 512, 1024, 768, 0, (long)1024 * 768, (long)512 * 1024, 0);
  // Pexp[b] = exp(q[b] k[b]^T * scale) -> bf16, + partial row-sums (softmax fused)
  k_gemm3<0, false, true, 3, 1><<<dim3(512), 512, 0, stream>>>(
      qb, kbuf, nullptr, nullptr, Sbuf, 4096, 1024, 512,
      (long)4096 * 512, (long)1024 * 512, (long)4096 * 1024, 0, nullptr, psums);
  // ctx_out[b] = (Pexp[b] @ vT[b]^T) / rowsum -> bf16 [8][4096][512]
  k_gemm3<0, false, true, 1, 2><<<dim3(256), 512, 0, stream>>>(
      Sbuf, vT, nullptr, nullptr, ctxb, 4096, 512, 1024,
      (long)4096 * 1024, (long)512 * 1024, (long)4096 * 512, 0, psums, nullptr);
  // out = ctx_out @ Wo + bo + x -> f32
  k_gemm3<1, true, false, 0, 0><<<dim3(128, 2, 1), 512, 0, stream>>>(
      ctxb, WoT, bo, x, out, 32768, 512, 512, 0, 0, 0, 0, nullptr, nullptr);
}

// Round 14
// 214.347 us; speedup vs baseline: 1.1757x; 1.0020x over previous
//
#include <hip/hip_runtime.h>

typedef __attribute__((ext_vector_type(8))) short short8;
typedef __attribute__((ext_vector_type(4))) float f32x4;
typedef __attribute__((ext_vector_type(4))) int i32x4;

#define NSEQ 4096
#define MSEQ 1024
#define HID  512
#define CTXD 768

static __device__ __forceinline__ unsigned short f2bf(float f) {
  union { float f; unsigned u; } v; v.f = f;
  return (unsigned short)((v.u + 0x7fffu + ((v.u >> 16) & 1u)) >> 16);
}
static __device__ __forceinline__ float bf2f(unsigned short u) {
  union { unsigned u; float f; } v; v.u = ((unsigned)u) << 16;
  return v.f;
}

static __device__ __forceinline__ void gld16(const void* g, void* l) {
  __builtin_amdgcn_global_load_lds((const __attribute__((address_space(1))) void*)g,
                                   (__attribute__((address_space(3))) void*)l, 16, 0, 0);
}

// ---------------- weight transpose: W[K][N] f32 -> WT[N][K] bf16 ----------------
__global__ void k_transpose(const float* __restrict__ W, unsigned short* __restrict__ WT,
                            int K, int N) {
  __shared__ float tile[32][33];
  int k0 = blockIdx.x * 32, n0 = blockIdx.y * 32;
  int tx = threadIdx.x, ty = threadIdx.y;
#pragma unroll
  for (int i = 0; i < 32; i += 8)
    tile[ty + i][tx] = W[(size_t)(k0 + ty + i) * N + n0 + tx];
  __syncthreads();
#pragma unroll
  for (int i = 0; i < 32; i += 8)
    WT[(size_t)(n0 + ty + i) * K + k0 + tx] = f2bf(tile[tx][ty + i]);
}

// ---------------- f32 -> bf16 cast, vectorized ----------------
__global__ void k_cast(const float* __restrict__ in, unsigned short* __restrict__ out, int n8) {
  int i = blockIdx.x * blockDim.x + threadIdx.x;
  int stride = gridDim.x * blockDim.x;
  for (; i < n8; i += stride) {
    f32x4 v0 = *(const f32x4*)(in + (size_t)i * 8);
    f32x4 v1 = *(const f32x4*)(in + (size_t)i * 8 + 4);
    unsigned short tmp[8] __attribute__((aligned(16)));
    tmp[0] = f2bf(v0[0]); tmp[1] = f2bf(v0[1]); tmp[2] = f2bf(v0[2]); tmp[3] = f2bf(v0[3]);
    tmp[4] = f2bf(v1[0]); tmp[5] = f2bf(v1[1]); tmp[6] = f2bf(v1[2]); tmp[7] = f2bf(v1[3]);
    *(i32x4*)(out + (size_t)i * 8) = *(const i32x4*)tmp;
  }
}

// ---------------- GEMM 128x128 (R2-proven): C = A[M][K] * BT[N][K]^T ------------
// ZMODE 0: grid (mx,ny,nz). ZMODE 2: flat grid, z=bid&7, r=bid>>3, m=r>>3, n=r&7.
template<int BIAS_MODE, bool RES, bool OUT_BF16, int ZMODE>
__global__ __launch_bounds__(256, 2) void k_gemm(
    const unsigned short* __restrict__ A, const unsigned short* __restrict__ B,
    const float* __restrict__ bias, const float* __restrict__ resv,
    void* __restrict__ Cv, int M, int N, int K,
    long sA, long sB, long sC, long sR) {
  __shared__ __align__(16) char lds[65536];
  const int t = threadIdx.x, lane = t & 63, wid = t >> 6;
  const int wr = wid >> 1, wc = wid & 1;
  int m0, n0, z;
  if (ZMODE == 2) {
    int bid = blockIdx.x; z = bid & 7; int r = bid >> 3;
    m0 = (r >> 3) * 128; n0 = (r & 7) * 128;
  } else {
    m0 = blockIdx.x * 128; n0 = blockIdx.y * 128; z = blockIdx.z;
  }
  const unsigned short* Ab = A + (size_t)z * sA;
  const unsigned short* Bb = B + (size_t)z * sB;

  const f32x4 fz = {0.f, 0.f, 0.f, 0.f};
  f32x4 acc[4][4];
#pragma unroll
  for (int i = 0; i < 4; i++)
#pragma unroll
    for (int j = 0; j < 4; j++) acc[i][j] = fz;

  const int srow = t >> 3;      // 0..31
  const int schunk = t & 7;

  auto stage = [&](int kk, int buf) {
    const char* a8 = (const char*)Ab;
    const char* b8 = (const char*)Bb;
#pragma unroll
    for (int i = 0; i < 4; i++) {
      int row = i * 32 + srow;
      gld16(a8 + ((size_t)(m0 + row) * K + kk) * 2 + ((schunk ^ (row & 7)) << 4),
            lds + buf * 32768 + i * 4096 + wid * 1024);
    }
#pragma unroll
    for (int i = 0; i < 4; i++) {
      int row = i * 32 + srow;
      gld16(b8 + ((size_t)(n0 + row) * K + kk) * 2 + ((schunk ^ (row & 7)) << 4),
            lds + buf * 32768 + 16384 + i * 4096 + wid * 1024);
    }
  };

  stage(0, 0);
  int buf = 0;
  for (int kk = 0; kk < K; kk += 64) {
    if (kk + 64 < K) {
      stage(kk + 64, buf ^ 1);
      asm volatile("s_waitcnt vmcnt(8)" ::: "memory");
    } else {
      asm volatile("s_waitcnt vmcnt(0)" ::: "memory");
    }
    __builtin_amdgcn_s_barrier();
    const char* As = lds + buf * 32768;
    const char* Bs = As + 16384;
#pragma unroll
    for (int ks = 0; ks < 2; ks++) {
      short8 af[4], bfr[4];
#pragma unroll
      for (int i = 0; i < 4; i++) {
        int r = wr * 64 + i * 16 + (lane & 15);
        af[i] = *(const short8*)(As + r * 128 +
                 (((unsigned)(ks * 64 + (lane >> 4) * 16)) ^ ((unsigned)(r & 7) << 4)));
      }
#pragma unroll
      for (int i = 0; i < 4; i++) {
        int r = wc * 64 + i * 16 + (lane & 15);
        bfr[i] = *(const short8*)(Bs + r * 128 +
                 (((unsigned)(ks * 64 + (lane >> 4) * 16)) ^ ((unsigned)(r & 7) << 4)));
      }
#pragma unroll
      for (int i = 0; i < 4; i++)
#pragma unroll
        for (int j = 0; j < 4; j++)
          acc[i][j] = __builtin_amdgcn_mfma_f32_16x16x32_bf16(af[i], bfr[j], acc[i][j], 0, 0, 0);
    }
    asm volatile("s_waitcnt lgkmcnt(0)" ::: "memory");
    __builtin_amdgcn_s_barrier();
    buf ^= 1;
  }

  const float* res = RES ? (resv + (size_t)z * sR) : nullptr;
  char* Cb = (char*)Cv + (size_t)z * sC * (OUT_BF16 ? 2 : 4);
#pragma unroll
  for (int i = 0; i < 4; i++) {
#pragma unroll
    for (int jj = 0; jj < 4; jj++) {
      int row = m0 + wr * 64 + i * 16 + (lane >> 4) * 4 + jj;
#pragma unroll
      for (int j = 0; j < 4; j++) {
        int col = n0 + wc * 64 + j * 16 + (lane & 15);
        float v = acc[i][j][jj];
        if (BIAS_MODE == 1) v += bias[col];
        if (BIAS_MODE == 2) v += bias[row];
        if (RES) v += res[(size_t)row * N + col];
        if (OUT_BF16) ((unsigned short*)Cb)[(size_t)row * N + col] = f2bf(v);
        else          ((float*)Cb)[(size_t)row * N + col] = v;
      }
    }
  }
}

// ---------------- GEMM 256x256, BK=32, 8 waves (2x4), 3-buffer ring -------------
// Single-phase K-loop, ONE barrier per tile, COMPILER-SCHEDULED lgkmcnt:
// every loaded fragment is consumed by an MFMA inside the same barrier region
// (s_barrier = scheduler region boundary), so each wave's reads of slot tt%3
// are drained before it crosses barrier(tt+1) -- the first point where that
// slot becomes a staging target. Empty asm memory fences stop IR-level motion
// across the barrier. Reads issued bfr-first, af ascending, so the compiler's
// counted lgkmcnt overlaps the af[4..7] reads under the first MFMAs.
// ZMODE 0: grid (mx,ny,nz). ZMODE 1: flat, z=bid&7, r=bid>>3, m=r>>1, n=r&1.
// ZMODE 3: flat, z=bid&7, r=bid>>3, m=r>>2, n=r&3.
// EPI 0: bias/res. EPI 1: bf16(exp(acc*scale)) + deterministic partial row-sums.
// EPI 2: multiply by 1/(sum of 4 partials) before store (PV normalize).
template<int BIAS_MODE, bool RES, bool OUT_BF16, int ZMODE, int EPI>
__global__ __launch_bounds__(512, 1) void k_gemm3(
    const unsigned short* __restrict__ A, const unsigned short* __restrict__ B,
    const float* __restrict__ bias, const float* __restrict__ resv,
    void* __restrict__ Cv, int M, int N, int K,
    long sA, long sB, long sC, long sR,
    const float* __restrict__ ps, float* __restrict__ psout) {
  __shared__ __align__(16) char lds[98304];   // 3 x (A 16K + B 16K)
  const int t = threadIdx.x, lane = t & 63, wid = t >> 6;
  const int wr = wid >> 2, wc = wid & 3;
  const int l15 = lane & 15, g = lane >> 4;
  int m0, n0, z;
  if (ZMODE == 1) {
    int bid = blockIdx.x; z = bid & 7; int r = bid >> 3;
    m0 = (r >> 1) * 256; n0 = (r & 1) * 256;
  } else if (ZMODE == 3) {
    int bid = blockIdx.x; z = bid & 7; int r = bid >> 3;
    m0 = (r >> 2) * 256; n0 = (r & 3) * 256;
  } else {
    m0 = blockIdx.x * 256; n0 = blockIdx.y * 256; z = blockIdx.z;
  }
  const unsigned short* Ab = A + (size_t)z * sA;
  const unsigned short* Bb = B + (size_t)z * sB;

  const f32x4 fz = {0.f, 0.f, 0.f, 0.f};
  f32x4 acc[8][4];
#pragma unroll
  for (int i = 0; i < 8; i++)
#pragma unroll
    for (int j = 0; j < 4; j++) acc[i][j] = fz;

  // per-lane inverse map for staging: LDS byte p -> logical (row, colbyte)
  int rS[2], cS[2];
#pragma unroll
  for (int u = 0; u < 2; u++) {
    int p = u * 8192 + wid * 1024 + lane * 16;
    int L = p >> 7;
    int q = (p & 127) ^ ((L & 7) << 4);
    rS[u] = 2 * L + (q >> 6);
    cS[u] = q & 63;
  }

  auto stageA = [&](int kk, int buf, int u) {
    gld16((const char*)Ab + ((size_t)(m0 + rS[u]) * K + kk) * 2 + cS[u],
          lds + buf * 32768 + u * 8192 + wid * 1024);
  };
  auto stageB = [&](int kk, int buf, int u) {
    gld16((const char*)Bb + ((size_t)(n0 + rS[u]) * K + kk) * 2 + cS[u],
          lds + buf * 32768 + 16384 + u * 8192 + wid * 1024);
  };

  auto ldso = [&](int r, int gg) -> unsigned {
    unsigned L = (unsigned)(r >> 1);
    return L * 128 + ((((unsigned)(r & 1)) * 64 + (unsigned)gg * 16) ^ ((L & 7) << 4));
  };

  const int NT = K >> 5;
#pragma unroll
  for (int u = 0; u < 2; u++) { stageA(0, 0, u); }
#pragma unroll
  for (int u = 0; u < 2; u++) { stageB(0, 0, u); }
#pragma unroll
  for (int u = 0; u < 2; u++) { stageA(32, 1, u); }
#pragma unroll
  for (int u = 0; u < 2; u++) { stageB(32, 1, u); }

  for (int tt = 0; tt < NT; tt++) {
    if (tt + 1 < NT) { asm volatile("s_waitcnt vmcnt(4)" ::: "memory"); }
    else             { asm volatile("s_waitcnt vmcnt(0)" ::: "memory"); }
    __builtin_amdgcn_s_barrier();
    asm volatile("" ::: "memory");   // fence: no reads hoist above barrier
    const char* As = lds + (tt % 3) * 32768;
    const char* Bs = As + 16384;
    const int kk2 = (tt + 2) << 5;
    const bool st = kk2 < K;
    const int bn = (tt + 2) % 3;

    short8 bfr[4], af[8];
#pragma unroll
    for (int fj = 0; fj < 4; fj++) {
      int r = wc * 64 + fj * 16 + l15;
      bfr[fj] = *(const short8*)(Bs + ldso(r, g));
    }
#pragma unroll
    for (int fi = 0; fi < 8; fi++) {
      int r = wr * 128 + fi * 16 + l15;
      af[fi] = *(const short8*)(As + ldso(r, g));
    }
    if (st) { stageA(kk2, bn, 0); stageA(kk2, bn, 1); stageB(kk2, bn, 0); stageB(kk2, bn, 1); }
    __builtin_amdgcn_s_setprio(1);
#pragma unroll
    for (int fi = 0; fi < 8; fi++)
#pragma unroll
      for (int fj = 0; fj < 4; fj++)
        acc[fi][fj] =
            __builtin_amdgcn_mfma_f32_16x16x32_bf16(af[fi], bfr[fj], acc[fi][fj], 0, 0, 0);
    __builtin_amdgcn_s_setprio(0);
    asm volatile("" ::: "memory");   // fence: no reads sink below this point
  }
  asm volatile("s_waitcnt lgkmcnt(0)" ::: "memory");
  __builtin_amdgcn_s_barrier();   // protect LDS reuse in epilogue (EPI=1 redb)
  asm volatile("" ::: "memory");

  char* Cb = (char*)Cv + (size_t)z * sC * (OUT_BF16 ? 2 : 4);

  if (EPI == 1) {
    // exp epilogue: store bf16(exp(acc*scale)); deterministic partial row-sums.
    const float scale = 0.044194173824159216f;  // 512^-0.5
    float* redb = (float*)lds;                  // [4][256] (ring is dead)
#pragma unroll
    for (int i = 0; i < 8; i++) {
#pragma unroll
      for (int jj = 0; jj < 4; jj++) {
        int rl = wr * 128 + i * 16 + g * 4 + jj;   // row within tile
        int row = m0 + rl;
        float e4 = 0.f;
#pragma unroll
        for (int j = 0; j < 4; j++) {
          int col = n0 + wc * 64 + j * 16 + l15;
          float e = __expf(acc[i][j][jj] * scale);
          unsigned short h = f2bf(e);
          ((unsigned short*)Cb)[(size_t)row * N + col] = h;
          e4 += bf2f(h);
        }
#pragma unroll
        for (int d = 1; d < 16; d <<= 1) e4 += __shfl_xor(e4, d, 64);
        if (l15 == 0) redb[wc * 256 + rl] = e4;
      }
    }
    __syncthreads();
    if (t < 256) {
      float s4 = redb[t] + redb[256 + t] + redb[512 + t] + redb[768 + t];
      psout[(size_t)(n0 >> 8) * 32768 + (size_t)z * 4096 + (m0 + t)] = s4;
    }
    return;
  }

  const float* res = RES ? (resv + (size_t)z * sR) : nullptr;
#pragma unroll
  for (int i = 0; i < 8; i++) {
#pragma unroll
    for (int jj = 0; jj < 4; jj++) {
      int row = m0 + wr * 128 + i * 16 + g * 4 + jj;
      float inv = 1.0f;
      if (EPI == 2) {
        size_t r = (size_t)z * 4096 + row;
        inv = 1.0f / (ps[r] + ps[32768 + r] + ps[65536 + r] + ps[98304 + r]);
      }
#pragma unroll
      for (int j = 0; j < 4; j++) {
        int col = n0 + wc * 64 + j * 16 + l15;
        float v = acc[i][j][jj];
        if (EPI == 2) v *= inv;
        if (BIAS_MODE == 1) v += bias[col];
        if (BIAS_MODE == 2) v += bias[row];
        if (RES) v += res[(size_t)row * N + col];
        if (OUT_BF16) ((unsigned short*)Cb)[(size_t)row * N + col] = f2bf(v);
        else          ((float*)Cb)[(size_t)row * N + col] = v;
      }
    }
  }
}

// ---------------- launch ----------------
extern "C" void kernel_launch(void* const* d_in, const int* in_sizes, int n_in,
                              void* d_out, int out_size, void* d_ws, size_t ws_size,
                              hipStream_t stream) {
  (void)in_sizes; (void)n_in; (void)out_size; (void)ws_size;
  const float* x   = (const float*)d_in[0];
  const float* ctx = (const float*)d_in[1];
  const float* Wq  = (const float*)d_in[2];
  const float* bq  = (const float*)d_in[3];
  const float* Wk  = (const float*)d_in[4];
  const float* bk  = (const float*)d_in[5];
  const float* Wv  = (const float*)d_in[6];
  const float* bv  = (const float*)d_in[7];
  const float* Wo  = (const float*)d_in[8];
  const float* bo  = (const float*)d_in[9];
  float* out = (float*)d_out;

  char* ws = (char*)d_ws;
  unsigned short* qb   = (unsigned short*)(ws);              // 33,554,432
  unsigned short* kbuf = (unsigned short*)(ws + 33554432);   //  8,388,608
  unsigned short* vT   = (unsigned short*)(ws + 41943040);   //  8,388,608
  unsigned short* ctxb = (unsigned short*)(ws + 50331648);   // 33,554,432
  unsigned short* WqT  = (unsigned short*)(ws + 83886080);   //    524,288
  unsigned short* WkT  = (unsigned short*)(ws + 84410368);   //    786,432
  unsigned short* WvT  = (unsigned short*)(ws + 85196800);   //    786,432
  unsigned short* WoT  = (unsigned short*)(ws + 85983232);   //    524,288 -> 86,507,520
  // Sbuf overlays xb+cb (both dead by S-GEMM time)
  unsigned short* Sbuf = (unsigned short*)(ws + 86507520);   // 67,108,864 -> 153,616,384
  unsigned short* xb   = (unsigned short*)(ws + 86507520);   // 33,554,432
  unsigned short* cb   = (unsigned short*)(ws + 120061952);  // 12,582,912
  float* psums = (float*)(ws + 153616384);                   // 4*32768*4 = 524,288

  dim3 tb(32, 8);
  k_transpose<<<dim3(16, 16), tb, 0, stream>>>(Wq, WqT, 512, 512);
  k_transpose<<<dim3(24, 16), tb, 0, stream>>>(Wk, WkT, 768, 512);
  k_transpose<<<dim3(24, 16), tb, 0, stream>>>(Wv, WvT, 768, 512);
  k_transpose<<<dim3(16, 16), tb, 0, stream>>>(Wo, WoT, 512, 512);

  k_cast<<<dim3(2048), 256, 0, stream>>>(x,   xb, 2097152);
  k_cast<<<dim3(2048), 256, 0, stream>>>(ctx, cb,  786432);

  // q = x @ Wq + bq -> bf16 [32768][512]
  k_gemm3<1, false, true, 0, 0><<<dim3(128, 2, 1), 512, 0, stream>>>(
      xb, WqT, bq, nullptr, qb, 32768, 512, 512, 0, 0, 0, 0, nullptr, nullptr);
  // k = ctx @ Wk + bk -> bf16 [8192][512]
  k_gemm<1, false, true, 0><<<dim3(64, 4, 1), 256, 0, stream>>>(
      cb, WkT, bk, nullptr, kbuf, 8192, 512, 768, 0, 0, 0, 0);
  // vT[b] = (ctx[b] @ Wv + bv)^T -> bf16 [8][512][1024]  (z->XCD affinity)
  k_gemm<2, false, true, 2><<<dim3(256), 256, 0, stream>>>(
      WvT, cb, bv, nullptr, vT, 512, 1024, 768, 0, (long)1024 * 768, (long)512 * 1024, 0);
  // Pexp[b] = exp(q[b] k[b]^T * scale) -> bf16, + partial row-sums (softmax fused)
  k_gemm3<0, false, true, 3, 1><<<dim3(512), 512, 0, stream>>>(
      qb, kbuf, nullptr, nullptr, Sbuf, 4096, 1024, 512,
      (long)4096 * 512, (long)1024 * 512, (long)4096 * 1024, 0, nullptr, psums);
  // ctx_out[b] = (Pexp[b] @ vT[b]^T) / rowsum -> bf16 [8][4096][512]
  k_gemm3<0, false, true, 1, 2><<<dim3(256), 512, 0, stream>>>(
      Sbuf, vT, nullptr, nullptr, ctxb, 4096, 512, 1024,
      (long)4096 * 1024, (long)512 * 1024, (long)4096 * 512, 0, psums, nullptr);
  // out = ctx_out @ Wo + bo + x -> f32
  k_gemm3<1, true, false, 0, 0><<<dim3(128, 2, 1), 512, 0, stream>>>(
      ctxb, WoT, bo, x, out, 32768, 512, 512, 0, 0, 0, 0, nullptr, nullptr);
}